// Round 3
// baseline (5261.858 us; speedup 1.0000x reference)
//
#include <hip/hip_runtime.h>

#define B 8
#define NOBJ 128
#define NATTR 4
#define T 12
#define MC 2048
#define E 128
#define IDD 64
#define AD 64
#define HD 256
#define C 2176
#define NBLK 272

typedef short s16x8 __attribute__((ext_vector_type(8)));
typedef float f32x4 __attribute__((ext_vector_type(4)));

__device__ inline unsigned short f2b(float f) {
  union { float f; unsigned u; } v; v.f = f;
  unsigned r = v.u + 0x7FFFu + ((v.u >> 16) & 1u);
  return (unsigned short)(r >> 16);
}
__device__ inline float b2f(unsigned short u) {
  union { unsigned u; float f; } v; v.u = ((unsigned)u) << 16;
  return v.f;
}

// LDS swizzles: XOR row bits into the 16B-slot index (conflict-free b128 reads)
__device__ __forceinline__ int sidx(int d, int j) {   // sia [128][64]
  return d * 64 + ((((j >> 3) ^ (d & 7)) << 3) | (j & 7));
}
__device__ __forceinline__ int gidx(int r, int c) {   // g [64][128]
  return r * 128 + ((((c >> 3) ^ (r & 15)) << 3) | (c & 7));
}
__device__ __forceinline__ int hidx(int r, int c) {   // h [64][256]
  return r * 256 + ((((c >> 3) ^ (r & 15)) << 3) | (c & 7));
}

__device__ __forceinline__ void gridbar(unsigned int* bar) {
  __threadfence();
  __syncthreads();
  if (threadIdx.x == 0) {
    unsigned g = __hip_atomic_load(bar + 1, __ATOMIC_RELAXED, __HIP_MEMORY_SCOPE_AGENT);
    unsigned arr = __hip_atomic_fetch_add(bar, 1u, __ATOMIC_ACQ_REL, __HIP_MEMORY_SCOPE_AGENT);
    if (arr == NBLK - 1) {
      __hip_atomic_store(bar, 0u, __ATOMIC_RELAXED, __HIP_MEMORY_SCOPE_AGENT);
      __hip_atomic_fetch_add(bar + 1, 1u, __ATOMIC_ACQ_REL, __HIP_MEMORY_SCOPE_AGENT);
    } else {
      while (__hip_atomic_load(bar + 1, __ATOMIC_ACQUIRE, __HIP_MEMORY_SCOPE_AGENT) == g) {
        __builtin_amdgcn_s_sleep(2);
      }
    }
  }
  __syncthreads();
  __threadfence();
}

__global__ void k_zero(unsigned int* bar) {
  if (threadIdx.x < 2) bar[threadIdx.x] = 0u;
}

// ---------------- setup kernels ----------------

__global__ void k_build(const int* __restrict__ scene,
                        const float* __restrict__ aein, const float* __restrict__ aeout,
                        const float* __restrict__ aeid,
                        const float* __restrict__ cein, const float* __restrict__ ceout,
                        const float* __restrict__ ceid,
                        unsigned short* __restrict__ dendron_bf, float* __restrict__ axon,
                        float* __restrict__ identity) {
  int bj = blockIdx.x;          // b*C + j
  int b = bj / C, j = bj % C;
  int e = threadIdx.x;          // 0..127
  float din, dout, did = 0.f;
  if (j < MC) {
    din  = cein[j * E + e];
    dout = ceout[j * E + e];
    if (e < IDD) did = ceid[j * IDD + e];
  } else {
    int obj = j - MC;
    float sIn = 0.f, sOut = 0.f, sId = 0.f;
    for (int a = 0; a < NATTR; a++) {
      int s = scene[(b * NOBJ + obj) * NATTR + a];
      float m = (s != -1) ? 1.f : 0.f;
      int idx = s + 1;
      sIn  += aein[idx * E + e] * m;
      sOut += aeout[idx * E + e] * m;
      if (e < IDD) sId += aeid[idx * IDD + e] * m;
    }
    din = sIn; dout = sOut; did = sId;
  }
  dendron_bf[(size_t)(b * C + j) * E + e] = f2b(din);
  axon[(size_t)(b * C + j) * E + e] = dout;
  if (e < IDD) identity[(size_t)(b * C + j) * IDD + e] = did;
}

__global__ void k_cvtw(const float* __restrict__ aw1, const float* __restrict__ aw2,
                       const float* __restrict__ mw1, const float* __restrict__ mw2,
                       unsigned short* __restrict__ w1_bf, unsigned short* __restrict__ w2_bf,
                       float* __restrict__ mw1T, float* __restrict__ mw2T) {
  int i = blockIdx.x * 256 + threadIdx.x;
  if (i < HD * E)  w1_bf[i] = f2b(aw1[i]);
  if (i < AD * HD) w2_bf[i] = f2b(aw2[i]);
  if (i < 192 * HD) { int c = i / HD, k = i % HD; mw1T[c * HD + k] = mw1[k * 192 + c]; }
  if (i < HD * AD)  { int k = i / AD, a = i % AD; mw2T[k * AD + a] = mw2[a * HD + k]; }
}

// transpose axon -> axonT bf16 [b][e][j], identity -> idT_g bf16 [b][d][j]
__global__ __launch_bounds__(256) void k_transA(const float* __restrict__ axon,
                                                const float* __restrict__ identity,
                                                unsigned short* __restrict__ axonT,
                                                unsigned short* __restrict__ idT_g) {
  int b = blockIdx.x / 34, jc = blockIdx.x % 34;
  int j0 = jc * 64;
  __shared__ float ax[64][129];
  __shared__ float idb[64][65];
  int tid = threadIdx.x;
  for (int i = tid; i < 64 * 128; i += 256) {
    int j = i >> 7, e = i & 127;
    ax[j][e] = axon[(size_t)(b * C + j0 + j) * E + e];
  }
  for (int i = tid; i < 64 * 64; i += 256) {
    int j = i >> 6, d = i & 63;
    idb[j][d] = identity[(size_t)(b * C + j0 + j) * IDD + d];
  }
  __syncthreads();
  for (int i = tid; i < 128 * 64; i += 256) {
    int e = i >> 6, jj = i & 63;
    axonT[(size_t)(b * E + e) * C + j0 + jj] = f2b(ax[jj][e]);
  }
  for (int i = tid; i < 64 * 64; i += 256) {
    int d = i >> 6, jj = i & 63;
    idT_g[(size_t)(b * 64 + d) * C + j0 + jj] = f2b(idb[jj][d]);
  }
}

// sequential meta scan
__global__ void k_meta(const int* __restrict__ prog_op, const int* __restrict__ prog_arg,
                       const float* __restrict__ ceout,
                       const float* __restrict__ mw1T, const float* __restrict__ mb1,
                       const float* __restrict__ mw2T, const float* __restrict__ mb2,
                       const float* __restrict__ att_init, float* __restrict__ meta_all) {
  int b = blockIdx.x;
  __shared__ float x[192];
  __shared__ float h[HD];
  __shared__ float meta[AD];
  int tid = threadIdx.x;
  if (tid < AD) meta[tid] = att_init[tid];
  __syncthreads();
  for (int t = 0; t < T; t++) {
    int arg = prog_arg[b * T + t];
    if (tid < AD) x[tid] = meta[tid];
    else if (tid < 192) x[tid] = ceout[arg * E + (tid - 64)];
    __syncthreads();
    float s = mb1[tid];
    for (int c = 0; c < 192; c++) s += x[c] * mw1T[c * HD + tid];
    h[tid] = fmaxf(s, 0.f);
    __syncthreads();
    if (tid < AD) {
      float o = mb2[tid];
      for (int k = 0; k < HD; k++) o += h[k] * mw2T[k * AD + tid];
      float m = (prog_op[b * T + t] == 0) ? 1.f : 0.f;
      float nm = m * o + (1.f - m) * meta[tid];
      meta[tid] = nm;
      meta_all[(t * B + b) * AD + tid] = nm;
    }
    __syncthreads();
  }
}

__global__ void k_proj(const int* __restrict__ prog_arg, const float* __restrict__ ceout,
                       const float* __restrict__ axon, float* __restrict__ proj_all) {
  int gid = blockIdx.x * 4 + (threadIdx.x >> 6);
  int lane = threadIdx.x & 63;
  if (gid >= B * C) return;
  int b = gid / C, i = gid % C;
  float a0 = axon[(size_t)(b * C + i) * E + lane];
  float a1 = axon[(size_t)(b * C + i) * E + 64 + lane];
  for (int t = 0; t < T; t++) {
    int arg = prog_arg[b * T + t];
    float p = a0 * ceout[arg * E + lane] + a1 * ceout[arg * E + 64 + lane];
    for (int off = 1; off < 64; off <<= 1) p += __shfl_xor(p, off, 64);
    if (lane == 0) proj_all[(size_t)(t * B + b) * C + i] = p * (1.f / E);
  }
}

// ---------------- the fused 12-step persistent kernel ----------------

typedef union {
  unsigned short sia[128 * 64];                                   // 16 KB (S1)
  struct { unsigned short g[64 * 128]; unsigned short h[64 * 256]; } s3;  // 48 KB (S3)
} Ubuf;

__global__ __launch_bounds__(256, 2) void k_coop(
    const unsigned short* __restrict__ dendron_bf,
    const unsigned short* __restrict__ axonT,
    const unsigned short* __restrict__ idT_g,
    const unsigned short* __restrict__ w1_bf,
    const unsigned short* __restrict__ w2_bf,
    const float* __restrict__ b1g, const float* __restrict__ b2g,
    const float* __restrict__ proj_all, const float* __restrict__ meta_all,
    const int* __restrict__ prog_op, const float* __restrict__ att_init,
    unsigned short* __restrict__ Mpart, unsigned short* __restrict__ Mt,
    float* __restrict__ rowmean,
    float* __restrict__ att_hist, float* __restrict__ ins_hist,
    float* __restrict__ trans_hist, unsigned int* __restrict__ bar) {
  const int blk = blockIdx.x;
  const int b = blk / 34, ch = blk % 34, j0 = ch * 64;
  const int tid = threadIdx.x;
  const int w = tid >> 6, lane = tid & 63, lr = lane & 15, lg = lane >> 4;

  __shared__ unsigned short idT[64 * 64];
  __shared__ Ubuf u;
  __shared__ float am_l[64];

  for (int i = tid; i < 64 * 64; i += 256) {
    int d = i >> 6, j = i & 63;
    idT[d * 64 + j] = idT_g[(size_t)(b * 64 + d) * C + j0 + j];
  }
  // attention state in registers: att[n][v] = att[row = w*16+lg*4+v][col = n*16+lr]
  float att[4][4];
  #pragma unroll
  for (int n = 0; n < 4; n++) {
    float v0 = att_init[n * 16 + lr];
    #pragma unroll
    for (int v = 0; v < 4; v++) att[n][v] = v0;
  }
  __syncthreads();

  const f32x4 z = {0.f, 0.f, 0.f, 0.f};
  for (int t = 0; t < T; t++) {
    // ---- S1a: row means (shfl tree over the 16 lr lanes) ----
    {
      float s[4];
      #pragma unroll
      for (int v = 0; v < 4; v++) s[v] = att[0][v] + att[1][v] + att[2][v] + att[3][v];
      #pragma unroll
      for (int v = 0; v < 4; v++) {
        s[v] += __shfl_xor(s[v], 1, 64);
        s[v] += __shfl_xor(s[v], 2, 64);
        s[v] += __shfl_xor(s[v], 4, 64);
        s[v] += __shfl_xor(s[v], 8, 64);
      }
      if (lr == 0) {
        #pragma unroll
        for (int v = 0; v < 4; v++) am_l[w * 16 + lg * 4 + v] = s[v] * (1.f / AD);
      }
    }
    __syncthreads();
    // ---- S1b: build sia (bf16, swizzled): d<64 identity part, d>=64 attention part ----
    for (int i = tid; i < 64 * 64; i += 256) {
      int d = i >> 6, j = i & 63;
      u.sia[sidx(d, j)] = f2b(b2f(idT[d * 64 + j]) * am_l[j]);
    }
    {
      float amr[4];
      #pragma unroll
      for (int v = 0; v < 4; v++) amr[v] = am_l[w * 16 + lg * 4 + v];
      #pragma unroll
      for (int n = 0; n < 4; n++)
        #pragma unroll
        for (int v = 0; v < 4; v++)
          u.sia[sidx(64 + n * 16 + lr, w * 16 + lg * 4 + v)] = f2b(att[n][v] * amr[v]);
    }
    __syncthreads();
    // ---- S1c: partial M over own 64 j: Mpart[blk][d][e] ----
    {
      s16x8 af[2][2];
      #pragma unroll
      for (int dt = 0; dt < 2; dt++) {
        int d0 = (w * 2 + dt) * 16;
        af[dt][0] = *(const s16x8*)&u.sia[sidx(d0 + lr, lg * 8)];
        af[dt][1] = *(const s16x8*)&u.sia[sidx(d0 + lr, 32 + lg * 8)];
      }
      unsigned short* mp = Mpart + (size_t)blk * 16384;
      #pragma unroll
      for (int et = 0; et < 8; et++) {
        const unsigned short* bp = axonT + (size_t)(b * E + et * 16 + lr) * C + j0 + lg * 8;
        s16x8 b0 = *(const s16x8*)bp;
        s16x8 b1 = *(const s16x8*)(bp + 32);
        #pragma unroll
        for (int dt = 0; dt < 2; dt++) {
          f32x4 acc = z;
          acc = __builtin_amdgcn_mfma_f32_16x16x32_bf16(af[dt][0], b0, acc, 0, 0, 0);
          acc = __builtin_amdgcn_mfma_f32_16x16x32_bf16(af[dt][1], b1, acc, 0, 0, 0);
          int d0 = (w * 2 + dt) * 16;
          #pragma unroll
          for (int v = 0; v < 4; v++)
            mp[(d0 + lg * 4 + v) * 128 + et * 16 + lr] = f2b(acc[v]);
        }
      }
    }
    gridbar(bar);
    // ---- S2: reduce partials (fixed order, deterministic) ----
    if (ch < 32) {
      #pragma unroll
      for (int r = 0; r < 2; r++) {
        int f = ch * 512 + r * 256 + tid;
        float ssum = 0.f;
        const unsigned short* p = Mpart + (size_t)b * 34 * 16384 + f;
        for (int c2 = 0; c2 < 34; c2++) ssum += b2f(p[(size_t)c2 * 16384]);
        Mt[(size_t)b * 16384 + f] = f2b(ssum);
      }
    }
    gridbar(bar);
    // ---- S3 phase A: g = dendron @ M / C ----
    {
      const int i0g = j0 + w * 16;
      s16x8 afr[4];
      #pragma unroll
      for (int ke = 0; ke < 4; ke++)
        afr[ke] = *(const s16x8*)(dendron_bf + (size_t)(b * C + i0g + lr) * E + ke * 32 + lg * 8);
      #pragma unroll
      for (int n = 0; n < 8; n++) {
        f32x4 acc = z;
        #pragma unroll
        for (int ke = 0; ke < 4; ke++) {
          s16x8 bf = *(const s16x8*)(Mt + (size_t)b * 16384 + (n * 16 + lr) * 128 + ke * 32 + lg * 8);
          acc = __builtin_amdgcn_mfma_f32_16x16x32_bf16(afr[ke], bf, acc, 0, 0, 0);
        }
        #pragma unroll
        for (int v = 0; v < 4; v++)
          u.s3.g[gidx(w * 16 + lg * 4 + v, n * 16 + lr)] = f2b(acc[v] * (1.f / C));
      }
    }
    __syncthreads();
    // ---- S3 phase B: h = relu(g @ w1^T + b1) ----
    {
      s16x8 gf[4];
      #pragma unroll
      for (int kd = 0; kd < 4; kd++)
        gf[kd] = *(const s16x8*)&u.s3.g[gidx(w * 16 + lr, kd * 32 + lg * 8)];
      #pragma unroll
      for (int n = 0; n < 16; n++) {
        f32x4 acc = z;
        #pragma unroll
        for (int kd = 0; kd < 4; kd++) {
          s16x8 bf = *(const s16x8*)(w1_bf + (size_t)(n * 16 + lr) * E + kd * 32 + lg * 8);
          acc = __builtin_amdgcn_mfma_f32_16x16x32_bf16(gf[kd], bf, acc, 0, 0, 0);
        }
        float b1v = b1g[n * 16 + lr];
        #pragma unroll
        for (int v = 0; v < 4; v++)
          u.s3.h[hidx(w * 16 + lg * 4 + v, n * 16 + lr)] = f2b(fmaxf(acc[v] + b1v, 0.f));
      }
    }
    __syncthreads();
    // ---- S3 phase C: out = h @ w2^T ; epilogue updates att regs + hist ----
    {
      s16x8 hf[8];
      #pragma unroll
      for (int kk = 0; kk < 8; kk++)
        hf[kk] = *(const s16x8*)&u.s3.h[hidx(w * 16 + lr, kk * 32 + lg * 8)];
      int op = prog_op[b * T + t];
      float insF = (op == 1) ? 1.f : 0.f, trF = (op == 2) ? 1.f : 0.f;
      float projv[4];
      #pragma unroll
      for (int v = 0; v < 4; v++)
        projv[v] = proj_all[(size_t)(t * B + b) * C + j0 + w * 16 + lg * 4 + v];
      #pragma unroll
      for (int n = 0; n < 4; n++) {
        f32x4 acc = z;
        #pragma unroll
        for (int kk = 0; kk < 8; kk++) {
          s16x8 bf = *(const s16x8*)(w2_bf + (size_t)(n * 16 + lr) * HD + kk * 32 + lg * 8);
          acc = __builtin_amdgcn_mfma_f32_16x16x32_bf16(hf[kk], bf, acc, 0, 0, 0);
        }
        int a = n * 16 + lr;
        float b2v = b2g[a];
        float meta_a = meta_all[(size_t)(t * B + b) * AD + a];
        #pragma unroll
        for (int v = 0; v < 4; v++) {
          int row = lg * 4 + v;
          int i = j0 + w * 16 + row;
          float transfer = acc[v] + b2v + b2f(u.s3.g[gidx(w * 16 + row, 64 + a)]);
          float insert = meta_a * projv[v];
          float attv = att[n][v] + insF * insert + trF * transfer;
          attv = (attv >= 0.f) ? attv : 0.01f * attv;
          attv = fminf(fmaxf(attv, -1.f), 2.f);
          att[n][v] = attv;
          size_t hi = (((size_t)t * B + b) * C + i) * AD + a;
          att_hist[hi] = attv;
          ins_hist[hi] = insert;
          trans_hist[hi] = transfer;
        }
      }
    }
  }
  // ---- final row means for softmax ----
  {
    float s[4];
    #pragma unroll
    for (int v = 0; v < 4; v++) s[v] = att[0][v] + att[1][v] + att[2][v] + att[3][v];
    #pragma unroll
    for (int v = 0; v < 4; v++) {
      s[v] += __shfl_xor(s[v], 1, 64);
      s[v] += __shfl_xor(s[v], 2, 64);
      s[v] += __shfl_xor(s[v], 4, 64);
      s[v] += __shfl_xor(s[v], 8, 64);
    }
    if (lr == 0) {
      #pragma unroll
      for (int v = 0; v < 4; v++)
        rowmean[(size_t)b * C + j0 + w * 16 + lg * 4 + v] = s[v] * (1.f / AD);
    }
  }
}

// ---------------- final softmax ----------------
__global__ void k_softmax(const float* __restrict__ rowmean, float* __restrict__ out) {
  int b = blockIdx.x;
  __shared__ float am[C];
  __shared__ float red[256];
  int tid = threadIdx.x;
  for (int i = tid; i < C; i += 256) am[i] = rowmean[(size_t)b * C + i];
  __syncthreads();
  float mx = -1e30f;
  for (int i = tid; i < C; i += 256) mx = fmaxf(mx, am[i]);
  red[tid] = mx; __syncthreads();
  for (int s = 128; s > 0; s >>= 1) { if (tid < s) red[tid] = fmaxf(red[tid], red[tid + s]); __syncthreads(); }
  mx = red[0]; __syncthreads();
  float sm = 0.f;
  for (int i = tid; i < C; i += 256) sm += expf(am[i] - mx);
  red[tid] = sm; __syncthreads();
  for (int s = 128; s > 0; s >>= 1) { if (tid < s) red[tid] += red[tid + s]; __syncthreads(); }
  float lse = logf(red[0]) + mx;
  for (int i = tid; i < C; i += 256) out[(size_t)b * C + i] = am[i] - lse;
}

extern "C" void kernel_launch(void* const* d_in, const int* in_sizes, int n_in,
                              void* d_out, int out_size, void* d_ws, size_t ws_size,
                              hipStream_t stream) {
  const int* scene     = (const int*)d_in[0];
  const int* prog_op   = (const int*)d_in[1];
  const int* prog_arg  = (const int*)d_in[2];
  const float* aein    = (const float*)d_in[3];
  const float* aeout   = (const float*)d_in[4];
  const float* aeid    = (const float*)d_in[5];
  const float* cein    = (const float*)d_in[6];
  const float* ceout   = (const float*)d_in[7];
  const float* ceid    = (const float*)d_in[8];
  const float* att_init = (const float*)d_in[11];
  const float* aw1 = (const float*)d_in[12];
  const float* ab1 = (const float*)d_in[13];
  const float* aw2 = (const float*)d_in[14];
  const float* ab2 = (const float*)d_in[15];
  const float* mw1 = (const float*)d_in[16];
  const float* mb1 = (const float*)d_in[17];
  const float* mw2 = (const float*)d_in[18];
  const float* mb2 = (const float*)d_in[19];

  char* ws = (char*)d_ws;
  size_t off = 0;
  auto carve = [&](size_t bytes) { char* p = ws + off; off += (bytes + 255) & ~(size_t)255; return p; };
  float* axon      = (float*)carve((size_t)B * C * E * 4);
  float* identity  = (float*)carve((size_t)B * C * IDD * 4);
  float* proj_all  = (float*)carve((size_t)T * B * C * 4);
  float* meta_all  = (float*)carve((size_t)T * B * AD * 4);
  float* mw1T      = (float*)carve((size_t)192 * HD * 4);
  float* mw2T      = (float*)carve((size_t)HD * AD * 4);
  float* rowmean   = (float*)carve((size_t)B * C * 4);
  unsigned short* dendron_bf = (unsigned short*)carve((size_t)B * C * E * 2);
  unsigned short* axonT      = (unsigned short*)carve((size_t)B * E * C * 2);
  unsigned short* idT_g      = (unsigned short*)carve((size_t)B * 64 * C * 2);
  unsigned short* Mpart      = (unsigned short*)carve((size_t)NBLK * 16384 * 2);
  unsigned short* Mt         = (unsigned short*)carve((size_t)B * 16384 * 2);
  unsigned short* w1_bf      = (unsigned short*)carve((size_t)HD * E * 2);
  unsigned short* w2_bf      = (unsigned short*)carve((size_t)AD * HD * 2);
  unsigned int*   bar        = (unsigned int*)carve(256);

  float* out_sm     = (float*)d_out;
  float* att_hist   = out_sm + B * C;
  float* ins_hist   = att_hist + (size_t)T * B * C * AD;
  float* trans_hist = ins_hist + (size_t)T * B * C * AD;

  k_build<<<dim3(B * C), dim3(E), 0, stream>>>(scene, aein, aeout, aeid, cein, ceout, ceid,
                                               dendron_bf, axon, identity);
  k_cvtw<<<dim3(192), dim3(256), 0, stream>>>(aw1, aw2, mw1, mw2, w1_bf, w2_bf, mw1T, mw2T);
  k_transA<<<dim3(B * 34), dim3(256), 0, stream>>>(axon, identity, axonT, idT_g);
  k_meta<<<dim3(B), dim3(256), 0, stream>>>(prog_op, prog_arg, ceout, mw1T, mb1, mw2T, mb2,
                                            att_init, meta_all);
  k_proj<<<dim3(B * C / 4), dim3(256), 0, stream>>>(prog_arg, ceout, axon, proj_all);
  k_zero<<<dim3(1), dim3(64), 0, stream>>>(bar);

  k_coop<<<dim3(NBLK), dim3(256), 0, stream>>>(dendron_bf, axonT, idT_g, w1_bf, w2_bf,
                                               ab1, ab2, proj_all, meta_all, prog_op, att_init,
                                               Mpart, Mt, rowmean,
                                               att_hist, ins_hist, trans_hist, bar);

  k_softmax<<<dim3(B), dim3(256), 0, stream>>>(rowmean, out_sm);
}

// Round 4
// 2542.106 us; speedup vs baseline: 2.0699x; 2.0699x over previous
//
#include <hip/hip_runtime.h>

#define B 8
#define NOBJ 128
#define NATTR 4
#define T 12
#define MC 2048
#define E 128
#define IDD 64
#define AD 64
#define HD 256
#define C 2176
#define NBLK 272

typedef short s16x8 __attribute__((ext_vector_type(8)));
typedef float f32x4 __attribute__((ext_vector_type(4)));

__device__ inline unsigned short f2b(float f) {
  union { float f; unsigned u; } v; v.f = f;
  unsigned r = v.u + 0x7FFFu + ((v.u >> 16) & 1u);
  return (unsigned short)(r >> 16);
}
__device__ inline float b2f(unsigned short u) {
  union { unsigned u; float f; } v; v.u = ((unsigned)u) << 16;
  return v.f;
}

// coherent (MALL-level) accessors: bypass non-coherent per-XCD L1/L2, no fences
__device__ __forceinline__ void st_coh_f32(float* p, float v) {
  union { float f; unsigned u; } c; c.f = v;
  __hip_atomic_store((unsigned*)p, c.u, __ATOMIC_RELAXED, __HIP_MEMORY_SCOPE_AGENT);
}
__device__ __forceinline__ unsigned long long ld_coh_u64(const unsigned long long* p) {
  return __hip_atomic_load(p, __ATOMIC_RELAXED, __HIP_MEMORY_SCOPE_AGENT);
}
__device__ __forceinline__ void st_coh_u32(unsigned* p, unsigned v) {
  __hip_atomic_store(p, v, __ATOMIC_RELAXED, __HIP_MEMORY_SCOPE_AGENT);
}

// LDS swizzles: XOR row bits into the 16B-slot index (conflict-free b128 reads)
__device__ __forceinline__ int sidx(int d, int j) {   // sia [128][64]
  return d * 64 + ((((j >> 3) ^ (d & 7)) << 3) | (j & 7));
}
__device__ __forceinline__ int gidx(int r, int c) {   // g [64][128]
  return r * 128 + ((((c >> 3) ^ (r & 15)) << 3) | (c & 7));
}
__device__ __forceinline__ int hidx(int r, int c) {   // h [64][256]
  return r * 256 + ((((c >> 3) ^ (r & 15)) << 3) | (c & 7));
}

// Fence-free grid barrier. __syncthreads drains vmcnt(0) per wave (all prior
// sc-flagged stores are MALL-visible); barrier protocol itself uses relaxed
// agent atomics only -> NO buffer_wbl2 / buffer_inv, L2 stays warm.
__device__ __forceinline__ void gridbar(unsigned int* bar) {
  __syncthreads();
  if (threadIdx.x == 0) {
    unsigned g = __hip_atomic_load(bar + 1, __ATOMIC_RELAXED, __HIP_MEMORY_SCOPE_AGENT);
    unsigned arr = __hip_atomic_fetch_add(bar, 1u, __ATOMIC_RELAXED, __HIP_MEMORY_SCOPE_AGENT);
    if (arr == NBLK - 1) {
      __hip_atomic_store(bar, 0u, __ATOMIC_RELAXED, __HIP_MEMORY_SCOPE_AGENT);
      __hip_atomic_fetch_add(bar + 1, 1u, __ATOMIC_RELAXED, __HIP_MEMORY_SCOPE_AGENT);
    } else {
      while (__hip_atomic_load(bar + 1, __ATOMIC_RELAXED, __HIP_MEMORY_SCOPE_AGENT) == g) {
        __builtin_amdgcn_s_sleep(8);
      }
    }
  }
  __syncthreads();
}

__global__ void k_zero(unsigned int* bar) {
  if (threadIdx.x < 2) bar[threadIdx.x] = 0u;
}

// ---------------- setup kernels ----------------

__global__ void k_build(const int* __restrict__ scene,
                        const float* __restrict__ aein, const float* __restrict__ aeout,
                        const float* __restrict__ aeid,
                        const float* __restrict__ cein, const float* __restrict__ ceout,
                        const float* __restrict__ ceid,
                        unsigned short* __restrict__ dendron_bf, float* __restrict__ axon,
                        float* __restrict__ identity) {
  int bj = blockIdx.x;          // b*C + j
  int b = bj / C, j = bj % C;
  int e = threadIdx.x;          // 0..127
  float din, dout, did = 0.f;
  if (j < MC) {
    din  = cein[j * E + e];
    dout = ceout[j * E + e];
    if (e < IDD) did = ceid[j * IDD + e];
  } else {
    int obj = j - MC;
    float sIn = 0.f, sOut = 0.f, sId = 0.f;
    for (int a = 0; a < NATTR; a++) {
      int s = scene[(b * NOBJ + obj) * NATTR + a];
      float m = (s != -1) ? 1.f : 0.f;
      int idx = s + 1;
      sIn  += aein[idx * E + e] * m;
      sOut += aeout[idx * E + e] * m;
      if (e < IDD) sId += aeid[idx * IDD + e] * m;
    }
    din = sIn; dout = sOut; did = sId;
  }
  dendron_bf[(size_t)(b * C + j) * E + e] = f2b(din);
  axon[(size_t)(b * C + j) * E + e] = dout;
  if (e < IDD) identity[(size_t)(b * C + j) * IDD + e] = did;
}

__global__ void k_cvtw(const float* __restrict__ aw1, const float* __restrict__ aw2,
                       const float* __restrict__ mw1, const float* __restrict__ mw2,
                       unsigned short* __restrict__ w1_bf, unsigned short* __restrict__ w2_bf,
                       float* __restrict__ mw1T, float* __restrict__ mw2T) {
  int i = blockIdx.x * 256 + threadIdx.x;
  if (i < HD * E)  w1_bf[i] = f2b(aw1[i]);
  if (i < AD * HD) w2_bf[i] = f2b(aw2[i]);
  if (i < 192 * HD) { int c = i / HD, k = i % HD; mw1T[c * HD + k] = mw1[k * 192 + c]; }
  if (i < HD * AD)  { int k = i / AD, a = i % AD; mw2T[k * AD + a] = mw2[a * HD + k]; }
}

// transpose axon -> axonT bf16 [b][e][j], identity -> idT_g bf16 [b][d][j]
__global__ __launch_bounds__(256) void k_transA(const float* __restrict__ axon,
                                                const float* __restrict__ identity,
                                                unsigned short* __restrict__ axonT,
                                                unsigned short* __restrict__ idT_g) {
  int b = blockIdx.x / 34, jc = blockIdx.x % 34;
  int j0 = jc * 64;
  __shared__ float ax[64][129];
  __shared__ float idb[64][65];
  int tid = threadIdx.x;
  for (int i = tid; i < 64 * 128; i += 256) {
    int j = i >> 7, e = i & 127;
    ax[j][e] = axon[(size_t)(b * C + j0 + j) * E + e];
  }
  for (int i = tid; i < 64 * 64; i += 256) {
    int j = i >> 6, d = i & 63;
    idb[j][d] = identity[(size_t)(b * C + j0 + j) * IDD + d];
  }
  __syncthreads();
  for (int i = tid; i < 128 * 64; i += 256) {
    int e = i >> 6, jj = i & 63;
    axonT[(size_t)(b * E + e) * C + j0 + jj] = f2b(ax[jj][e]);
  }
  for (int i = tid; i < 64 * 64; i += 256) {
    int d = i >> 6, jj = i & 63;
    idT_g[(size_t)(b * 64 + d) * C + j0 + jj] = f2b(idb[jj][d]);
  }
}

// sequential meta scan
__global__ void k_meta(const int* __restrict__ prog_op, const int* __restrict__ prog_arg,
                       const float* __restrict__ ceout,
                       const float* __restrict__ mw1T, const float* __restrict__ mb1,
                       const float* __restrict__ mw2T, const float* __restrict__ mb2,
                       const float* __restrict__ att_init, float* __restrict__ meta_all) {
  int b = blockIdx.x;
  __shared__ float x[192];
  __shared__ float h[HD];
  __shared__ float meta[AD];
  int tid = threadIdx.x;
  if (tid < AD) meta[tid] = att_init[tid];
  __syncthreads();
  for (int t = 0; t < T; t++) {
    int arg = prog_arg[b * T + t];
    if (tid < AD) x[tid] = meta[tid];
    else if (tid < 192) x[tid] = ceout[arg * E + (tid - 64)];
    __syncthreads();
    float s = mb1[tid];
    for (int c = 0; c < 192; c++) s += x[c] * mw1T[c * HD + tid];
    h[tid] = fmaxf(s, 0.f);
    __syncthreads();
    if (tid < AD) {
      float o = mb2[tid];
      for (int k = 0; k < HD; k++) o += h[k] * mw2T[k * AD + tid];
      float m = (prog_op[b * T + t] == 0) ? 1.f : 0.f;
      float nm = m * o + (1.f - m) * meta[tid];
      meta[tid] = nm;
      meta_all[(t * B + b) * AD + tid] = nm;
    }
    __syncthreads();
  }
}

__global__ void k_proj(const int* __restrict__ prog_arg, const float* __restrict__ ceout,
                       const float* __restrict__ axon, float* __restrict__ proj_all) {
  int gid = blockIdx.x * 4 + (threadIdx.x >> 6);
  int lane = threadIdx.x & 63;
  if (gid >= B * C) return;
  int b = gid / C, i = gid % C;
  float a0 = axon[(size_t)(b * C + i) * E + lane];
  float a1 = axon[(size_t)(b * C + i) * E + 64 + lane];
  for (int t = 0; t < T; t++) {
    int arg = prog_arg[b * T + t];
    float p = a0 * ceout[arg * E + lane] + a1 * ceout[arg * E + 64 + lane];
    for (int off = 1; off < 64; off <<= 1) p += __shfl_xor(p, off, 64);
    if (lane == 0) proj_all[(size_t)(t * B + b) * C + i] = p * (1.f / E);
  }
}

// ---------------- the fused 12-step persistent kernel ----------------

typedef union {
  unsigned short sia[128 * 64];                                   // 16 KB (S1)
  struct { unsigned short g[64 * 128]; unsigned short h[64 * 256]; } s3;  // 48 KB (S3)
} Ubuf;

__global__ __launch_bounds__(256, 2) void k_coop(
    const unsigned short* __restrict__ dendron_bf,
    const unsigned short* __restrict__ axonT,
    const unsigned short* __restrict__ idT_g,
    const unsigned short* __restrict__ w1_bf,
    const unsigned short* __restrict__ w2_bf,
    const float* __restrict__ b1g, const float* __restrict__ b2g,
    const float* __restrict__ proj_all, const float* __restrict__ meta_all,
    const int* __restrict__ prog_op, const float* __restrict__ att_init,
    float* __restrict__ Mpart, unsigned* __restrict__ Mt32,
    float* __restrict__ rowmean,
    float* __restrict__ att_hist, float* __restrict__ ins_hist,
    float* __restrict__ trans_hist, unsigned int* __restrict__ bar) {
  const int blk = blockIdx.x;
  const int b = blk / 34, ch = blk % 34, j0 = ch * 64;
  const int tid = threadIdx.x;
  const int w = tid >> 6, lane = tid & 63, lr = lane & 15, lg = lane >> 4;

  __shared__ unsigned short idT[64 * 64];
  __shared__ Ubuf u;
  __shared__ float am_l[64];

  for (int i = tid; i < 64 * 64; i += 256) {
    int d = i >> 6, j = i & 63;
    idT[d * 64 + j] = idT_g[(size_t)(b * 64 + d) * C + j0 + j];
  }
  // attention state in registers: att[n][v] = att[row = w*16+lg*4+v][col = n*16+lr]
  float att[4][4];
  #pragma unroll
  for (int n = 0; n < 4; n++) {
    float v0 = att_init[n * 16 + lr];
    #pragma unroll
    for (int v = 0; v < 4; v++) att[n][v] = v0;
  }
  __syncthreads();

  const f32x4 z = {0.f, 0.f, 0.f, 0.f};
  for (int t = 0; t < T; t++) {
    // ---- S1a: row means (shfl tree over the 16 lr lanes) ----
    {
      float s[4];
      #pragma unroll
      for (int v = 0; v < 4; v++) s[v] = att[0][v] + att[1][v] + att[2][v] + att[3][v];
      #pragma unroll
      for (int v = 0; v < 4; v++) {
        s[v] += __shfl_xor(s[v], 1, 64);
        s[v] += __shfl_xor(s[v], 2, 64);
        s[v] += __shfl_xor(s[v], 4, 64);
        s[v] += __shfl_xor(s[v], 8, 64);
      }
      if (lr == 0) {
        #pragma unroll
        for (int v = 0; v < 4; v++) am_l[w * 16 + lg * 4 + v] = s[v] * (1.f / AD);
      }
    }
    __syncthreads();
    // ---- S1b: build sia (bf16, swizzled LDS) ----
    for (int i = tid; i < 64 * 64; i += 256) {
      int d = i >> 6, j = i & 63;
      u.sia[sidx(d, j)] = f2b(b2f(idT[d * 64 + j]) * am_l[j]);
    }
    {
      float amr[4];
      #pragma unroll
      for (int v = 0; v < 4; v++) amr[v] = am_l[w * 16 + lg * 4 + v];
      #pragma unroll
      for (int n = 0; n < 4; n++)
        #pragma unroll
        for (int v = 0; v < 4; v++)
          u.sia[sidx(64 + n * 16 + lr, w * 16 + lg * 4 + v)] = f2b(att[n][v] * amr[v]);
    }
    __syncthreads();
    // ---- S1c: partial M over own 64 j -> Mpart[blk][d][e] (fp32, coherent stores) ----
    {
      s16x8 af[2][2];
      #pragma unroll
      for (int dt = 0; dt < 2; dt++) {
        int d0 = (w * 2 + dt) * 16;
        af[dt][0] = *(const s16x8*)&u.sia[sidx(d0 + lr, lg * 8)];
        af[dt][1] = *(const s16x8*)&u.sia[sidx(d0 + lr, 32 + lg * 8)];
      }
      float* mp = Mpart + (size_t)blk * 16384;
      #pragma unroll
      for (int et = 0; et < 8; et++) {
        const unsigned short* bp = axonT + (size_t)(b * E + et * 16 + lr) * C + j0 + lg * 8;
        s16x8 b0 = *(const s16x8*)bp;
        s16x8 b1 = *(const s16x8*)(bp + 32);
        #pragma unroll
        for (int dt = 0; dt < 2; dt++) {
          f32x4 acc = z;
          acc = __builtin_amdgcn_mfma_f32_16x16x32_bf16(af[dt][0], b0, acc, 0, 0, 0);
          acc = __builtin_amdgcn_mfma_f32_16x16x32_bf16(af[dt][1], b1, acc, 0, 0, 0);
          int d0 = (w * 2 + dt) * 16;
          #pragma unroll
          for (int v = 0; v < 4; v++)
            st_coh_f32(mp + (d0 + lg * 4 + v) * 128 + et * 16 + lr, acc[v]);
        }
      }
    }
    gridbar(bar);
    // ---- S2: fixed-order reduce of 34 partials -> Mt (bf16 pairs in u32) ----
    if (ch < 16) {
      const unsigned long long* pb = (const unsigned long long*)Mpart + (size_t)b * 34 * 8192;
      #pragma unroll
      for (int r = 0; r < 2; r++) {
        int s = ch * 512 + r * 256 + tid;            // u32-pair slot: f = 2s, 2s+1
        float s0 = 0.f, s1 = 0.f;
        for (int c2 = 0; c2 < 34; c2++) {
          union { unsigned long long u; float f[2]; } cv;
          cv.u = ld_coh_u64(pb + (size_t)c2 * 8192 + s);
          s0 += cv.f[0]; s1 += cv.f[1];
        }
        unsigned packed = (unsigned)f2b(s0) | ((unsigned)f2b(s1) << 16);
        st_coh_u32(Mt32 + (size_t)b * 8192 + s, packed);
      }
    }
    gridbar(bar);
    // ---- S3 phase A: g = dendron @ M / C  (Mt coherent u64 loads) ----
    {
      const int i0g = j0 + w * 16;
      const unsigned long long* mtp = (const unsigned long long*)Mt32 + (size_t)b * 4096;
      s16x8 afr[4];
      #pragma unroll
      for (int ke = 0; ke < 4; ke++)
        afr[ke] = *(const s16x8*)(dendron_bf + (size_t)(b * C + i0g + lr) * E + ke * 32 + lg * 8);
      #pragma unroll
      for (int n = 0; n < 8; n++) {
        f32x4 acc = z;
        #pragma unroll
        for (int ke = 0; ke < 4; ke++) {
          union { unsigned long long u[2]; s16x8 v; } fb;
          int base = (n * 16 + lr) * 32 + ke * 8 + lg * 2;
          fb.u[0] = ld_coh_u64(mtp + base);
          fb.u[1] = ld_coh_u64(mtp + base + 1);
          acc = __builtin_amdgcn_mfma_f32_16x16x32_bf16(afr[ke], fb.v, acc, 0, 0, 0);
        }
        #pragma unroll
        for (int v = 0; v < 4; v++)
          u.s3.g[gidx(w * 16 + lg * 4 + v, n * 16 + lr)] = f2b(acc[v] * (1.f / C));
      }
    }
    __syncthreads();
    // ---- S3 phase B: h = relu(g @ w1^T + b1) ----
    {
      s16x8 gf[4];
      #pragma unroll
      for (int kd = 0; kd < 4; kd++)
        gf[kd] = *(const s16x8*)&u.s3.g[gidx(w * 16 + lr, kd * 32 + lg * 8)];
      #pragma unroll
      for (int n = 0; n < 16; n++) {
        f32x4 acc = z;
        #pragma unroll
        for (int kd = 0; kd < 4; kd++) {
          s16x8 bf = *(const s16x8*)(w1_bf + (size_t)(n * 16 + lr) * E + kd * 32 + lg * 8);
          acc = __builtin_amdgcn_mfma_f32_16x16x32_bf16(gf[kd], bf, acc, 0, 0, 0);
        }
        float b1v = b1g[n * 16 + lr];
        #pragma unroll
        for (int v = 0; v < 4; v++)
          u.s3.h[hidx(w * 16 + lg * 4 + v, n * 16 + lr)] = f2b(fmaxf(acc[v] + b1v, 0.f));
      }
    }
    __syncthreads();
    // ---- S3 phase C: out = h @ w2^T ; epilogue updates att regs + hist ----
    {
      s16x8 hf[8];
      #pragma unroll
      for (int kk = 0; kk < 8; kk++)
        hf[kk] = *(const s16x8*)&u.s3.h[hidx(w * 16 + lr, kk * 32 + lg * 8)];
      int op = prog_op[b * T + t];
      float insF = (op == 1) ? 1.f : 0.f, trF = (op == 2) ? 1.f : 0.f;
      float projv[4];
      #pragma unroll
      for (int v = 0; v < 4; v++)
        projv[v] = proj_all[(size_t)(t * B + b) * C + j0 + w * 16 + lg * 4 + v];
      #pragma unroll
      for (int n = 0; n < 4; n++) {
        f32x4 acc = z;
        #pragma unroll
        for (int kk = 0; kk < 8; kk++) {
          s16x8 bf = *(const s16x8*)(w2_bf + (size_t)(n * 16 + lr) * HD + kk * 32 + lg * 8);
          acc = __builtin_amdgcn_mfma_f32_16x16x32_bf16(hf[kk], bf, acc, 0, 0, 0);
        }
        int a = n * 16 + lr;
        float b2v = b2g[a];
        float meta_a = meta_all[(size_t)(t * B + b) * AD + a];
        #pragma unroll
        for (int v = 0; v < 4; v++) {
          int row = lg * 4 + v;
          int i = j0 + w * 16 + row;
          float transfer = acc[v] + b2v + b2f(u.s3.g[gidx(w * 16 + row, 64 + a)]);
          float insert = meta_a * projv[v];
          float attv = att[n][v] + insF * insert + trF * transfer;
          attv = (attv >= 0.f) ? attv : 0.01f * attv;
          attv = fminf(fmaxf(attv, -1.f), 2.f);
          att[n][v] = attv;
          size_t hi = (((size_t)t * B + b) * C + i) * AD + a;
          __builtin_nontemporal_store(attv, att_hist + hi);
          __builtin_nontemporal_store(insert, ins_hist + hi);
          __builtin_nontemporal_store(transfer, trans_hist + hi);
        }
      }
    }
  }
  // ---- final row means for softmax ----
  {
    float s[4];
    #pragma unroll
    for (int v = 0; v < 4; v++) s[v] = att[0][v] + att[1][v] + att[2][v] + att[3][v];
    #pragma unroll
    for (int v = 0; v < 4; v++) {
      s[v] += __shfl_xor(s[v], 1, 64);
      s[v] += __shfl_xor(s[v], 2, 64);
      s[v] += __shfl_xor(s[v], 4, 64);
      s[v] += __shfl_xor(s[v], 8, 64);
    }
    if (lr == 0) {
      #pragma unroll
      for (int v = 0; v < 4; v++)
        rowmean[(size_t)b * C + j0 + w * 16 + lg * 4 + v] = s[v] * (1.f / AD);
    }
  }
}

// ---------------- final softmax ----------------
__global__ void k_softmax(const float* __restrict__ rowmean, float* __restrict__ out) {
  int b = blockIdx.x;
  __shared__ float am[C];
  __shared__ float red[256];
  int tid = threadIdx.x;
  for (int i = tid; i < C; i += 256) am[i] = rowmean[(size_t)b * C + i];
  __syncthreads();
  float mx = -1e30f;
  for (int i = tid; i < C; i += 256) mx = fmaxf(mx, am[i]);
  red[tid] = mx; __syncthreads();
  for (int s = 128; s > 0; s >>= 1) { if (tid < s) red[tid] = fmaxf(red[tid], red[tid + s]); __syncthreads(); }
  mx = red[0]; __syncthreads();
  float sm = 0.f;
  for (int i = tid; i < C; i += 256) sm += expf(am[i] - mx);
  red[tid] = sm; __syncthreads();
  for (int s = 128; s > 0; s >>= 1) { if (tid < s) red[tid] += red[tid + s]; __syncthreads(); }
  float lse = logf(red[0]) + mx;
  for (int i = tid; i < C; i += 256) out[(size_t)b * C + i] = am[i] - lse;
}

extern "C" void kernel_launch(void* const* d_in, const int* in_sizes, int n_in,
                              void* d_out, int out_size, void* d_ws, size_t ws_size,
                              hipStream_t stream) {
  const int* scene     = (const int*)d_in[0];
  const int* prog_op   = (const int*)d_in[1];
  const int* prog_arg  = (const int*)d_in[2];
  const float* aein    = (const float*)d_in[3];
  const float* aeout   = (const float*)d_in[4];
  const float* aeid    = (const float*)d_in[5];
  const float* cein    = (const float*)d_in[6];
  const float* ceout   = (const float*)d_in[7];
  const float* ceid    = (const float*)d_in[8];
  const float* att_init = (const float*)d_in[11];
  const float* aw1 = (const float*)d_in[12];
  const float* ab1 = (const float*)d_in[13];
  const float* aw2 = (const float*)d_in[14];
  const float* ab2 = (const float*)d_in[15];
  const float* mw1 = (const float*)d_in[16];
  const float* mb1 = (const float*)d_in[17];
  const float* mw2 = (const float*)d_in[18];
  const float* mb2 = (const float*)d_in[19];

  char* ws = (char*)d_ws;
  size_t off = 0;
  auto carve = [&](size_t bytes) { char* p = ws + off; off += (bytes + 255) & ~(size_t)255; return p; };
  float* axon      = (float*)carve((size_t)B * C * E * 4);
  float* identity  = (float*)carve((size_t)B * C * IDD * 4);
  float* proj_all  = (float*)carve((size_t)T * B * C * 4);
  float* meta_all  = (float*)carve((size_t)T * B * AD * 4);
  float* mw1T      = (float*)carve((size_t)192 * HD * 4);
  float* mw2T      = (float*)carve((size_t)HD * AD * 4);
  float* rowmean   = (float*)carve((size_t)B * C * 4);
  unsigned short* dendron_bf = (unsigned short*)carve((size_t)B * C * E * 2);
  unsigned short* axonT      = (unsigned short*)carve((size_t)B * E * C * 2);
  unsigned short* idT_g      = (unsigned short*)carve((size_t)B * 64 * C * 2);
  float*          Mpart      = (float*)carve((size_t)NBLK * 16384 * 4);
  unsigned*       Mt32       = (unsigned*)carve((size_t)B * 8192 * 4);
  unsigned short* w1_bf      = (unsigned short*)carve((size_t)HD * E * 2);
  unsigned short* w2_bf      = (unsigned short*)carve((size_t)AD * HD * 2);
  unsigned int*   bar        = (unsigned int*)carve(256);

  float* out_sm     = (float*)d_out;
  float* att_hist   = out_sm + B * C;
  float* ins_hist   = att_hist + (size_t)T * B * C * AD;
  float* trans_hist = ins_hist + (size_t)T * B * C * AD;

  k_build<<<dim3(B * C), dim3(E), 0, stream>>>(scene, aein, aeout, aeid, cein, ceout, ceid,
                                               dendron_bf, axon, identity);
  k_cvtw<<<dim3(192), dim3(256), 0, stream>>>(aw1, aw2, mw1, mw2, w1_bf, w2_bf, mw1T, mw2T);
  k_transA<<<dim3(B * 34), dim3(256), 0, stream>>>(axon, identity, axonT, idT_g);
  k_meta<<<dim3(B), dim3(256), 0, stream>>>(prog_op, prog_arg, ceout, mw1T, mb1, mw2T, mb2,
                                            att_init, meta_all);
  k_proj<<<dim3(B * C / 4), dim3(256), 0, stream>>>(prog_arg, ceout, axon, proj_all);
  k_zero<<<dim3(1), dim3(64), 0, stream>>>(bar);

  k_coop<<<dim3(NBLK), dim3(256), 0, stream>>>(dendron_bf, axonT, idT_g, w1_bf, w2_bf,
                                               ab1, ab2, proj_all, meta_all, prog_op, att_init,
                                               Mpart, Mt32, rowmean,
                                               att_hist, ins_hist, trans_hist, bar);

  k_softmax<<<dim3(B), dim3(256), 0, stream>>>(rowmean, out_sm);
}

// Round 5
// 1571.423 us; speedup vs baseline: 3.3485x; 1.6177x over previous
//
#include <hip/hip_runtime.h>

#define B 8
#define NOBJ 128
#define NATTR 4
#define T 12
#define MC 2048
#define E 128
#define IDD 64
#define AD 64
#define HD 256
#define C 2176
#define NBLK 272

typedef short s16x8 __attribute__((ext_vector_type(8)));
typedef float f32x4 __attribute__((ext_vector_type(4)));

__device__ inline unsigned short f2b(float f) {
  union { float f; unsigned u; } v; v.f = f;
  unsigned r = v.u + 0x7FFFu + ((v.u >> 16) & 1u);
  return (unsigned short)(r >> 16);
}
__device__ inline float b2f(unsigned short u) {
  union { unsigned u; float f; } v; v.u = ((unsigned)u) << 16;
  return v.f;
}

// coherent (MALL-level) accessors: bypass non-coherent per-XCD L1/L2, no fences
__device__ __forceinline__ void st_coh_f32(float* p, float v) {
  union { float f; unsigned u; } c; c.f = v;
  __hip_atomic_store((unsigned*)p, c.u, __ATOMIC_RELAXED, __HIP_MEMORY_SCOPE_AGENT);
}
__device__ __forceinline__ unsigned long long ld_coh_u64(const unsigned long long* p) {
  return __hip_atomic_load(p, __ATOMIC_RELAXED, __HIP_MEMORY_SCOPE_AGENT);
}
__device__ __forceinline__ void st_coh_u32(unsigned* p, unsigned v) {
  __hip_atomic_store(p, v, __ATOMIC_RELAXED, __HIP_MEMORY_SCOPE_AGENT);
}
__device__ __forceinline__ unsigned ld_coh_u32(const unsigned* p) {
  return __hip_atomic_load(p, __ATOMIC_RELAXED, __HIP_MEMORY_SCOPE_AGENT);
}

// LDS swizzles: XOR row bits into the 16B-slot index (conflict-free b128 reads)
__device__ __forceinline__ int sidx(int d, int j) {   // sia [128][64]
  return d * 64 + ((((j >> 3) ^ (d & 7)) << 3) | (j & 7));
}
__device__ __forceinline__ int gidx(int r, int c) {   // g [64][128]
  return r * 128 + ((((c >> 3) ^ (r & 15)) << 3) | (c & 7));
}
__device__ __forceinline__ int hidx(int r, int c) {   // h [64][256]
  return r * 256 + ((((c >> 3) ^ (r & 15)) << 3) | (c & 7));
}
__device__ __forceinline__ int mtidx(int r, int c) {  // mt [128][128]
  return r * 128 + ((((c >> 3) ^ (r & 15)) << 3) | (c & 7));
}

__global__ void k_zero(unsigned int* flags) {
  int i = threadIdx.x + blockIdx.x * 1024;
  if (i < 1024) flags[i] = 0u;
}

// ---------------- setup kernels ----------------

__global__ void k_build(const int* __restrict__ scene,
                        const float* __restrict__ aein, const float* __restrict__ aeout,
                        const float* __restrict__ aeid,
                        const float* __restrict__ cein, const float* __restrict__ ceout,
                        const float* __restrict__ ceid,
                        unsigned short* __restrict__ dendron_bf, float* __restrict__ axon,
                        float* __restrict__ identity) {
  int bj = blockIdx.x;          // b*C + j
  int b = bj / C, j = bj % C;
  int e = threadIdx.x;          // 0..127
  float din, dout, did = 0.f;
  if (j < MC) {
    din  = cein[j * E + e];
    dout = ceout[j * E + e];
    if (e < IDD) did = ceid[j * IDD + e];
  } else {
    int obj = j - MC;
    float sIn = 0.f, sOut = 0.f, sId = 0.f;
    for (int a = 0; a < NATTR; a++) {
      int s = scene[(b * NOBJ + obj) * NATTR + a];
      float m = (s != -1) ? 1.f : 0.f;
      int idx = s + 1;
      sIn  += aein[idx * E + e] * m;
      sOut += aeout[idx * E + e] * m;
      if (e < IDD) sId += aeid[idx * IDD + e] * m;
    }
    din = sIn; dout = sOut; did = sId;
  }
  dendron_bf[(size_t)(b * C + j) * E + e] = f2b(din);
  axon[(size_t)(b * C + j) * E + e] = dout;
  if (e < IDD) identity[(size_t)(b * C + j) * IDD + e] = did;
}

__global__ void k_cvtw(const float* __restrict__ aw1, const float* __restrict__ aw2,
                       const float* __restrict__ mw1, const float* __restrict__ mw2,
                       unsigned short* __restrict__ w1_bf, unsigned short* __restrict__ w2_bf,
                       float* __restrict__ mw1T, float* __restrict__ mw2T) {
  int i = blockIdx.x * 256 + threadIdx.x;
  if (i < HD * E)  w1_bf[i] = f2b(aw1[i]);
  if (i < AD * HD) w2_bf[i] = f2b(aw2[i]);
  if (i < 192 * HD) { int c = i / HD, k = i % HD; mw1T[c * HD + k] = mw1[k * 192 + c]; }
  if (i < HD * AD)  { int k = i / AD, a = i % AD; mw2T[k * AD + a] = mw2[a * HD + k]; }
}

// transpose axon -> axonT bf16 [b][e][j], identity -> idT_g bf16 [b][d][j]
__global__ __launch_bounds__(256) void k_transA(const float* __restrict__ axon,
                                                const float* __restrict__ identity,
                                                unsigned short* __restrict__ axonT,
                                                unsigned short* __restrict__ idT_g) {
  int b = blockIdx.x / 34, jc = blockIdx.x % 34;
  int j0 = jc * 64;
  __shared__ float ax[64][129];
  __shared__ float idb[64][65];
  int tid = threadIdx.x;
  for (int i = tid; i < 64 * 128; i += 256) {
    int j = i >> 7, e = i & 127;
    ax[j][e] = axon[(size_t)(b * C + j0 + j) * E + e];
  }
  for (int i = tid; i < 64 * 64; i += 256) {
    int j = i >> 6, d = i & 63;
    idb[j][d] = identity[(size_t)(b * C + j0 + j) * IDD + d];
  }
  __syncthreads();
  for (int i = tid; i < 128 * 64; i += 256) {
    int e = i >> 6, jj = i & 63;
    axonT[(size_t)(b * E + e) * C + j0 + jj] = f2b(ax[jj][e]);
  }
  for (int i = tid; i < 64 * 64; i += 256) {
    int d = i >> 6, jj = i & 63;
    idT_g[(size_t)(b * 64 + d) * C + j0 + jj] = f2b(idb[jj][d]);
  }
}

// sequential meta scan
__global__ void k_meta(const int* __restrict__ prog_op, const int* __restrict__ prog_arg,
                       const float* __restrict__ ceout,
                       const float* __restrict__ mw1T, const float* __restrict__ mb1,
                       const float* __restrict__ mw2T, const float* __restrict__ mb2,
                       const float* __restrict__ att_init, float* __restrict__ meta_all) {
  int b = blockIdx.x;
  __shared__ float x[192];
  __shared__ float h[HD];
  __shared__ float meta[AD];
  int tid = threadIdx.x;
  if (tid < AD) meta[tid] = att_init[tid];
  __syncthreads();
  for (int t = 0; t < T; t++) {
    int arg = prog_arg[b * T + t];
    if (tid < AD) x[tid] = meta[tid];
    else if (tid < 192) x[tid] = ceout[arg * E + (tid - 64)];
    __syncthreads();
    float s = mb1[tid];
    for (int c = 0; c < 192; c++) s += x[c] * mw1T[c * HD + tid];
    h[tid] = fmaxf(s, 0.f);
    __syncthreads();
    if (tid < AD) {
      float o = mb2[tid];
      for (int k = 0; k < HD; k++) o += h[k] * mw2T[k * AD + tid];
      float m = (prog_op[b * T + t] == 0) ? 1.f : 0.f;
      float nm = m * o + (1.f - m) * meta[tid];
      meta[tid] = nm;
      meta_all[(t * B + b) * AD + tid] = nm;
    }
    __syncthreads();
  }
}

__global__ void k_proj(const int* __restrict__ prog_arg, const float* __restrict__ ceout,
                       const float* __restrict__ axon, float* __restrict__ proj_all) {
  int gid = blockIdx.x * 4 + (threadIdx.x >> 6);
  int lane = threadIdx.x & 63;
  if (gid >= B * C) return;
  int b = gid / C, i = gid % C;
  float a0 = axon[(size_t)(b * C + i) * E + lane];
  float a1 = axon[(size_t)(b * C + i) * E + 64 + lane];
  for (int t = 0; t < T; t++) {
    int arg = prog_arg[b * T + t];
    float p = a0 * ceout[arg * E + lane] + a1 * ceout[arg * E + 64 + lane];
    for (int off = 1; off < 64; off <<= 1) p += __shfl_xor(p, off, 64);
    if (lane == 0) proj_all[(size_t)(t * B + b) * C + i] = p * (1.f / E);
  }
}

// ---------------- the fused 12-step persistent kernel ----------------
// LDS overlay: [0,16K) = sia OR g ; [16K,48K) = mt OR h (time-disjoint uses)

__global__ __launch_bounds__(256, 2) void k_coop(
    const unsigned short* __restrict__ dendron_bf,
    const unsigned short* __restrict__ axonT,
    const unsigned short* __restrict__ idT_g,
    const unsigned short* __restrict__ w1_bf,
    const unsigned short* __restrict__ w2_bf,
    const float* __restrict__ b1g, const float* __restrict__ b2g,
    const float* __restrict__ proj_all, const float* __restrict__ meta_all,
    const int* __restrict__ prog_op, const float* __restrict__ att_init,
    float* __restrict__ Mpart, unsigned* __restrict__ Mt32,
    float* __restrict__ rowmean,
    float* __restrict__ att_hist, float* __restrict__ ins_hist,
    float* __restrict__ trans_hist,
    unsigned int* __restrict__ f1,       // arrive flags [B][64]
    unsigned int* __restrict__ r1) {     // ready  flags [B][32]
  const int blk = blockIdx.x;
  const int b = blk / 34, ch = blk % 34, j0 = ch * 64;
  const int tid = threadIdx.x;
  const int w = tid >> 6, lane = tid & 63, lr = lane & 15, lg = lane >> 4;

  __shared__ unsigned short idT[64 * 64];          // 8 KB, persistent
  __shared__ unsigned short smem[24576];           // 48 KB overlay
  __shared__ float am_l[64];
  unsigned short* sia = smem;                      // [0,16K)
  unsigned short* g_l = smem;                      // [0,16K)
  unsigned short* mt  = smem + 8192;               // [16K,48K)
  unsigned short* h_l = smem + 8192;               // [16K,48K)

  for (int i = tid; i < 64 * 64; i += 256) {
    int d = i >> 6, j = i & 63;
    idT[d * 64 + j] = idT_g[(size_t)(b * 64 + d) * C + j0 + j];
  }
  // attention state in registers: att[n][v] = att[row = w*16+lg*4+v][col = n*16+lr]
  float att[4][4];
  #pragma unroll
  for (int n = 0; n < 4; n++) {
    float v0 = att_init[n * 16 + lr];
    #pragma unroll
    for (int v = 0; v < 4; v++) att[n][v] = v0;
  }
  // step-invariant dendron A-fragments (phase A), hoisted out of the t-loop
  s16x8 afr[4];
  {
    const int i0g = j0 + w * 16;
    #pragma unroll
    for (int ke = 0; ke < 4; ke++)
      afr[ke] = *(const s16x8*)(dendron_bf + (size_t)(b * C + i0g + lr) * E + ke * 32 + lg * 8);
  }
  __syncthreads();

  const f32x4 z = {0.f, 0.f, 0.f, 0.f};
  for (int t = 0; t < T; t++) {
    const unsigned ph = (unsigned)(t + 1);
    // ---- S1a: row means (shfl tree over the 16 lr lanes) ----
    {
      float s[4];
      #pragma unroll
      for (int v = 0; v < 4; v++) s[v] = att[0][v] + att[1][v] + att[2][v] + att[3][v];
      #pragma unroll
      for (int v = 0; v < 4; v++) {
        s[v] += __shfl_xor(s[v], 1, 64);
        s[v] += __shfl_xor(s[v], 2, 64);
        s[v] += __shfl_xor(s[v], 4, 64);
        s[v] += __shfl_xor(s[v], 8, 64);
      }
      if (lr == 0) {
        #pragma unroll
        for (int v = 0; v < 4; v++) am_l[w * 16 + lg * 4 + v] = s[v] * (1.f / AD);
      }
    }
    __syncthreads();
    // ---- S1b: build sia (bf16, swizzled LDS) ----
    for (int i = tid; i < 64 * 64; i += 256) {
      int d = i >> 6, j = i & 63;
      sia[sidx(d, j)] = f2b(b2f(idT[d * 64 + j]) * am_l[j]);
    }
    {
      float amr[4];
      #pragma unroll
      for (int v = 0; v < 4; v++) amr[v] = am_l[w * 16 + lg * 4 + v];
      #pragma unroll
      for (int n = 0; n < 4; n++)
        #pragma unroll
        for (int v = 0; v < 4; v++)
          sia[sidx(64 + n * 16 + lr, w * 16 + lg * 4 + v)] = f2b(att[n][v] * amr[v]);
    }
    __syncthreads();
    // ---- S1c: partial M over own 64 j -> Mpart[blk][d][e] (fp32, coherent stores) ----
    {
      s16x8 af[2][2];
      #pragma unroll
      for (int dt = 0; dt < 2; dt++) {
        int d0 = (w * 2 + dt) * 16;
        af[dt][0] = *(const s16x8*)&sia[sidx(d0 + lr, lg * 8)];
        af[dt][1] = *(const s16x8*)&sia[sidx(d0 + lr, 32 + lg * 8)];
      }
      float* mp = Mpart + (size_t)blk * 16384;
      #pragma unroll
      for (int et = 0; et < 8; et++) {
        const unsigned short* bp = axonT + (size_t)(b * E + et * 16 + lr) * C + j0 + lg * 8;
        s16x8 b0 = *(const s16x8*)bp;
        s16x8 b1 = *(const s16x8*)(bp + 32);
        #pragma unroll
        for (int dt = 0; dt < 2; dt++) {
          f32x4 acc = z;
          acc = __builtin_amdgcn_mfma_f32_16x16x32_bf16(af[dt][0], b0, acc, 0, 0, 0);
          acc = __builtin_amdgcn_mfma_f32_16x16x32_bf16(af[dt][1], b1, acc, 0, 0, 0);
          int d0 = (w * 2 + dt) * 16;
          #pragma unroll
          for (int v = 0; v < 4; v++)
            st_coh_f32(mp + (d0 + lg * 4 + v) * 128 + et * 16 + lr, acc[v]);
        }
      }
    }
    // ---- arrive: own flag, no RMW ----
    asm volatile("s_waitcnt vmcnt(0)" ::: "memory");
    __syncthreads();
    if (tid == 0) st_coh_u32(f1 + b * 64 + ch, ph);
    // ---- S2 (32 reducer blocks per batch): wait 34 arrivals, reduce, publish ----
    if (ch < 32) {
      if (tid < 34) {
        while (ld_coh_u32(f1 + b * 64 + tid) < ph) __builtin_amdgcn_s_sleep(1);
      }
      __syncthreads();
      int s = ch * 256 + tid;                      // u64-pair slot in [0,8192)
      const unsigned long long* pb = (const unsigned long long*)Mpart + (size_t)b * 34 * 8192;
      float s0 = 0.f, s1 = 0.f;
      #pragma unroll
      for (int c2 = 0; c2 < 34; c2++) {
        union { unsigned long long u; float f[2]; } cv;
        cv.u = ld_coh_u64(pb + (size_t)c2 * 8192 + s);
        s0 += cv.f[0]; s1 += cv.f[1];
      }
      unsigned packed = (unsigned)f2b(s0) | ((unsigned)f2b(s1) << 16);
      st_coh_u32(Mt32 + (size_t)b * 8192 + s, packed);
      asm volatile("s_waitcnt vmcnt(0)" ::: "memory");
      __syncthreads();
      if (tid == 0) st_coh_u32(r1 + b * 32 + ch, ph);
    }
    // ---- all blocks: wait for the 32 ready flags of this batch ----
    if (tid < 32) {
      while (ld_coh_u32(r1 + b * 32 + tid) < ph) __builtin_amdgcn_s_sleep(1);
    }
    __syncthreads();
    // ---- S3 phase A: stage Mt -> LDS (swizzled), then g = dendron @ M / C ----
    {
      const unsigned long long* mtp = (const unsigned long long*)Mt32 + (size_t)b * 4096;
      #pragma unroll
      for (int k = 0; k < 16; k++) {
        int idx = tid + k * 256;                   // u64 index in [0,4096)
        unsigned long long v = ld_coh_u64(mtp + idx);
        int r = idx >> 5, c4 = (idx & 31) * 4;
        *(unsigned long long*)&mt[mtidx(r, c4)] = v;
      }
    }
    __syncthreads();
    {
      #pragma unroll
      for (int n = 0; n < 8; n++) {
        f32x4 acc = z;
        #pragma unroll
        for (int ke = 0; ke < 4; ke++) {
          s16x8 bf = *(const s16x8*)&mt[mtidx(n * 16 + lr, ke * 32 + lg * 8)];
          acc = __builtin_amdgcn_mfma_f32_16x16x32_bf16(afr[ke], bf, acc, 0, 0, 0);
        }
        #pragma unroll
        for (int v = 0; v < 4; v++)
          g_l[gidx(w * 16 + lg * 4 + v, n * 16 + lr)] = f2b(acc[v] * (1.f / C));
      }
    }
    __syncthreads();
    // ---- S3 phase B: h = relu(g @ w1^T + b1)  (h overwrites mt region) ----
    {
      s16x8 gf[4];
      #pragma unroll
      for (int kd = 0; kd < 4; kd++)
        gf[kd] = *(const s16x8*)&g_l[gidx(w * 16 + lr, kd * 32 + lg * 8)];
      #pragma unroll
      for (int n = 0; n < 16; n++) {
        f32x4 acc = z;
        #pragma unroll
        for (int kd = 0; kd < 4; kd++) {
          s16x8 bf = *(const s16x8*)(w1_bf + (size_t)(n * 16 + lr) * E + kd * 32 + lg * 8);
          acc = __builtin_amdgcn_mfma_f32_16x16x32_bf16(gf[kd], bf, acc, 0, 0, 0);
        }
        float b1v = b1g[n * 16 + lr];
        #pragma unroll
        for (int v = 0; v < 4; v++)
          h_l[hidx(w * 16 + lg * 4 + v, n * 16 + lr)] = f2b(fmaxf(acc[v] + b1v, 0.f));
      }
    }
    __syncthreads();
    // ---- S3 phase C: out = h @ w2^T ; epilogue updates att regs + hist ----
    {
      s16x8 hf[8];
      #pragma unroll
      for (int kk = 0; kk < 8; kk++)
        hf[kk] = *(const s16x8*)&h_l[hidx(w * 16 + lr, kk * 32 + lg * 8)];
      int op = prog_op[b * T + t];
      float insF = (op == 1) ? 1.f : 0.f, trF = (op == 2) ? 1.f : 0.f;
      float projv[4];
      #pragma unroll
      for (int v = 0; v < 4; v++)
        projv[v] = proj_all[(size_t)(t * B + b) * C + j0 + w * 16 + lg * 4 + v];
      #pragma unroll
      for (int n = 0; n < 4; n++) {
        f32x4 acc = z;
        #pragma unroll
        for (int kk = 0; kk < 8; kk++) {
          s16x8 bf = *(const s16x8*)(w2_bf + (size_t)(n * 16 + lr) * HD + kk * 32 + lg * 8);
          acc = __builtin_amdgcn_mfma_f32_16x16x32_bf16(hf[kk], bf, acc, 0, 0, 0);
        }
        int a = n * 16 + lr;
        float b2v = b2g[a];
        float meta_a = meta_all[(size_t)(t * B + b) * AD + a];
        #pragma unroll
        for (int v = 0; v < 4; v++) {
          int row = lg * 4 + v;
          int i = j0 + w * 16 + row;
          float transfer = acc[v] + b2v + b2f(g_l[gidx(w * 16 + row, 64 + a)]);
          float insert = meta_a * projv[v];
          float attv = att[n][v] + insF * insert + trF * transfer;
          attv = (attv >= 0.f) ? attv : 0.01f * attv;
          attv = fminf(fmaxf(attv, -1.f), 2.f);
          att[n][v] = attv;
          size_t hi = (((size_t)t * B + b) * C + i) * AD + a;
          __builtin_nontemporal_store(attv, att_hist + hi);
          __builtin_nontemporal_store(insert, ins_hist + hi);
          __builtin_nontemporal_store(transfer, trans_hist + hi);
        }
      }
    }
    __syncthreads();   // protect g_l (read in C) before next step's sia overwrite
  }
  // ---- final row means for softmax ----
  {
    float s[4];
    #pragma unroll
    for (int v = 0; v < 4; v++) s[v] = att[0][v] + att[1][v] + att[2][v] + att[3][v];
    #pragma unroll
    for (int v = 0; v < 4; v++) {
      s[v] += __shfl_xor(s[v], 1, 64);
      s[v] += __shfl_xor(s[v], 2, 64);
      s[v] += __shfl_xor(s[v], 4, 64);
      s[v] += __shfl_xor(s[v], 8, 64);
    }
    if (lr == 0) {
      #pragma unroll
      for (int v = 0; v < 4; v++)
        rowmean[(size_t)b * C + j0 + w * 16 + lg * 4 + v] = s[v] * (1.f / AD);
    }
  }
}

// ---------------- final softmax ----------------
__global__ void k_softmax(const float* __restrict__ rowmean, float* __restrict__ out) {
  int b = blockIdx.x;
  __shared__ float am[C];
  __shared__ float red[256];
  int tid = threadIdx.x;
  for (int i = tid; i < C; i += 256) am[i] = rowmean[(size_t)b * C + i];
  __syncthreads();
  float mx = -1e30f;
  for (int i = tid; i < C; i += 256) mx = fmaxf(mx, am[i]);
  red[tid] = mx; __syncthreads();
  for (int s = 128; s > 0; s >>= 1) { if (tid < s) red[tid] = fmaxf(red[tid], red[tid + s]); __syncthreads(); }
  mx = red[0]; __syncthreads();
  float sm = 0.f;
  for (int i = tid; i < C; i += 256) sm += expf(am[i] - mx);
  red[tid] = sm; __syncthreads();
  for (int s = 128; s > 0; s >>= 1) { if (tid < s) red[tid] += red[tid + s]; __syncthreads(); }
  float lse = logf(red[0]) + mx;
  for (int i = tid; i < C; i += 256) out[(size_t)b * C + i] = am[i] - lse;
}

extern "C" void kernel_launch(void* const* d_in, const int* in_sizes, int n_in,
                              void* d_out, int out_size, void* d_ws, size_t ws_size,
                              hipStream_t stream) {
  const int* scene     = (const int*)d_in[0];
  const int* prog_op   = (const int*)d_in[1];
  const int* prog_arg  = (const int*)d_in[2];
  const float* aein    = (const float*)d_in[3];
  const float* aeout   = (const float*)d_in[4];
  const float* aeid    = (const float*)d_in[5];
  const float* cein    = (const float*)d_in[6];
  const float* ceout   = (const float*)d_in[7];
  const float* ceid    = (const float*)d_in[8];
  const float* att_init = (const float*)d_in[11];
  const float* aw1 = (const float*)d_in[12];
  const float* ab1 = (const float*)d_in[13];
  const float* aw2 = (const float*)d_in[14];
  const float* ab2 = (const float*)d_in[15];
  const float* mw1 = (const float*)d_in[16];
  const float* mb1 = (const float*)d_in[17];
  const float* mw2 = (const float*)d_in[18];
  const float* mb2 = (const float*)d_in[19];

  char* ws = (char*)d_ws;
  size_t off = 0;
  auto carve = [&](size_t bytes) { char* p = ws + off; off += (bytes + 255) & ~(size_t)255; return p; };
  float* axon      = (float*)carve((size_t)B * C * E * 4);
  float* identity  = (float*)carve((size_t)B * C * IDD * 4);
  float* proj_all  = (float*)carve((size_t)T * B * C * 4);
  float* meta_all  = (float*)carve((size_t)T * B * AD * 4);
  float* mw1T      = (float*)carve((size_t)192 * HD * 4);
  float* mw2T      = (float*)carve((size_t)HD * AD * 4);
  float* rowmean   = (float*)carve((size_t)B * C * 4);
  unsigned short* dendron_bf = (unsigned short*)carve((size_t)B * C * E * 2);
  unsigned short* axonT      = (unsigned short*)carve((size_t)B * E * C * 2);
  unsigned short* idT_g      = (unsigned short*)carve((size_t)B * 64 * C * 2);
  float*          Mpart      = (float*)carve((size_t)NBLK * 16384 * 4);
  unsigned*       Mt32       = (unsigned*)carve((size_t)B * 8192 * 4);
  unsigned short* w1_bf      = (unsigned short*)carve((size_t)HD * E * 2);
  unsigned short* w2_bf      = (unsigned short*)carve((size_t)AD * HD * 2);
  unsigned int*   flags      = (unsigned int*)carve(4096);   // f1[8][64] + r1[8][32]
  unsigned int*   f1 = flags;
  unsigned int*   r1 = flags + B * 64;

  float* out_sm     = (float*)d_out;
  float* att_hist   = out_sm + B * C;
  float* ins_hist   = att_hist + (size_t)T * B * C * AD;
  float* trans_hist = ins_hist + (size_t)T * B * C * AD;

  k_build<<<dim3(B * C), dim3(E), 0, stream>>>(scene, aein, aeout, aeid, cein, ceout, ceid,
                                               dendron_bf, axon, identity);
  k_cvtw<<<dim3(192), dim3(256), 0, stream>>>(aw1, aw2, mw1, mw2, w1_bf, w2_bf, mw1T, mw2T);
  k_transA<<<dim3(B * 34), dim3(256), 0, stream>>>(axon, identity, axonT, idT_g);
  k_meta<<<dim3(B), dim3(256), 0, stream>>>(prog_op, prog_arg, ceout, mw1T, mb1, mw2T, mb2,
                                            att_init, meta_all);
  k_proj<<<dim3(B * C / 4), dim3(256), 0, stream>>>(prog_arg, ceout, axon, proj_all);
  k_zero<<<dim3(1), dim3(1024), 0, stream>>>(flags);

  k_coop<<<dim3(NBLK), dim3(256), 0, stream>>>(dendron_bf, axonT, idT_g, w1_bf, w2_bf,
                                               ab1, ab2, proj_all, meta_all, prog_op, att_init,
                                               Mpart, Mt32, rowmean,
                                               att_hist, ins_hist, trans_hist, f1, r1);

  k_softmax<<<dim3(B), dim3(256), 0, stream>>>(rowmean, out_sm);
}

// Round 6
// 851.936 us; speedup vs baseline: 6.1764x; 1.8445x over previous
//
#include <hip/hip_runtime.h>

#define B 8
#define NOBJ 128
#define NATTR 4
#define T 12
#define MC 2048
#define E 128
#define IDD 64
#define AD 64
#define HD 256
#define C 2176

typedef short s16x8 __attribute__((ext_vector_type(8)));
typedef float f32x4 __attribute__((ext_vector_type(4)));

__device__ inline unsigned short f2b(float f) {
  union { float f; unsigned u; } v; v.f = f;
  unsigned r = v.u + 0x7FFFu + ((v.u >> 16) & 1u);
  return (unsigned short)(r >> 16);
}
__device__ inline float b2f(unsigned short u) {
  union { unsigned u; float f; } v; v.u = ((unsigned)u) << 16;
  return v.f;
}

// LDS swizzles: XOR row bits into the 16B-slot index (conflict-free b128 reads)
__device__ __forceinline__ int gidx(int r, int c) {   // g [64][128]
  return r * 128 + ((((c >> 3) ^ (r & 15)) << 3) | (c & 7));
}
__device__ __forceinline__ int hidx(int r, int c) {   // h [64][256]
  return r * 256 + ((((c >> 3) ^ (r & 15)) << 3) | (c & 7));
}
__device__ __forceinline__ int mtidx(int r, int c) {  // mt [128][128]
  return r * 128 + ((((c >> 3) ^ (r & 15)) << 3) | (c & 7));
}

// ---------------- setup kernels ----------------

__global__ void k_build(const int* __restrict__ scene,
                        const float* __restrict__ aein, const float* __restrict__ aeout,
                        const float* __restrict__ aeid,
                        const float* __restrict__ cein, const float* __restrict__ ceout,
                        const float* __restrict__ ceid,
                        unsigned short* __restrict__ dendron_bf, float* __restrict__ axon,
                        float* __restrict__ identity) {
  int bj = blockIdx.x;          // b*C + j
  int b = bj / C, j = bj % C;
  int e = threadIdx.x;          // 0..127
  float din, dout, did = 0.f;
  if (j < MC) {
    din  = cein[j * E + e];
    dout = ceout[j * E + e];
    if (e < IDD) did = ceid[j * IDD + e];
  } else {
    int obj = j - MC;
    float sIn = 0.f, sOut = 0.f, sId = 0.f;
    for (int a = 0; a < NATTR; a++) {
      int s = scene[(b * NOBJ + obj) * NATTR + a];
      float m = (s != -1) ? 1.f : 0.f;
      int idx = s + 1;
      sIn  += aein[idx * E + e] * m;
      sOut += aeout[idx * E + e] * m;
      if (e < IDD) sId += aeid[idx * IDD + e] * m;
    }
    din = sIn; dout = sOut; did = sId;
  }
  dendron_bf[(size_t)(b * C + j) * E + e] = f2b(din);
  axon[(size_t)(b * C + j) * E + e] = dout;
  if (e < IDD) identity[(size_t)(b * C + j) * IDD + e] = did;
}

__global__ void k_cvtw(const float* __restrict__ aw1, const float* __restrict__ aw2,
                       const float* __restrict__ mw1, const float* __restrict__ mw2,
                       unsigned short* __restrict__ w1_bf, unsigned short* __restrict__ w2_bf,
                       float* __restrict__ mw1T, float* __restrict__ mw2T) {
  int i = blockIdx.x * 256 + threadIdx.x;
  if (i < HD * E)  w1_bf[i] = f2b(aw1[i]);
  if (i < AD * HD) w2_bf[i] = f2b(aw2[i]);
  if (i < 192 * HD) { int c = i / HD, k = i % HD; mw1T[c * HD + k] = mw1[k * 192 + c]; }
  if (i < HD * AD)  { int k = i / AD, a = i % AD; mw2T[k * AD + a] = mw2[a * HD + k]; }
}

// transpose axon -> axonT bf16 [b][e][j], identity -> idT_g bf16 [b][d][j],
// and initialize siaT(0) + att_g(0) from att_init.
__global__ __launch_bounds__(256) void k_transA(const float* __restrict__ axon,
                                                const float* __restrict__ identity,
                                                const float* __restrict__ att_init,
                                                unsigned short* __restrict__ axonT,
                                                unsigned short* __restrict__ idT_g,
                                                unsigned short* __restrict__ siaT,
                                                float* __restrict__ att_g) {
  int blk = blockIdx.x;
  int b = blk / 34, jc = blk % 34;
  int j0 = jc * 64;
  __shared__ float ax[64][129];
  __shared__ float idb[64][65];
  int tid = threadIdx.x;
  int lane = tid & 63, lr = lane & 15;
  // am0 = mean(att_init) via full-wave shfl reduce
  float a0v = att_init[lane];
  float s = a0v;
  s += __shfl_xor(s, 1, 64);  s += __shfl_xor(s, 2, 64);
  s += __shfl_xor(s, 4, 64);  s += __shfl_xor(s, 8, 64);
  s += __shfl_xor(s, 16, 64); s += __shfl_xor(s, 32, 64);
  float am0 = s * (1.f / AD);
  for (int i = tid; i < 64 * 128; i += 256) {
    int j = i >> 7, e = i & 127;
    ax[j][e] = axon[(size_t)(b * C + j0 + j) * E + e];
  }
  for (int i = tid; i < 64 * 64; i += 256) {
    int j = i >> 6, d = i & 63;
    idb[j][d] = identity[(size_t)(b * C + j0 + j) * IDD + d];
  }
  __syncthreads();
  for (int i = tid; i < 128 * 64; i += 256) {
    int e = i >> 6, jj = i & 63;
    axonT[(size_t)(b * E + e) * C + j0 + jj] = f2b(ax[jj][e]);
  }
  for (int i = tid; i < 64 * 64; i += 256) {
    int d = i >> 6, jj = i & 63;
    unsigned short iv = f2b(idb[jj][d]);
    idT_g[(size_t)(b * 64 + d) * C + j0 + jj] = iv;
    siaT[(size_t)(b * 128 + d) * C + j0 + jj] = f2b(idb[jj][d] * am0);   // id half
    siaT[(size_t)(b * 128 + 64 + d) * C + j0 + jj] = f2b(att_init[d] * am0); // att half
  }
  // att_g(0): blocked layout matching k_row2: att[n][v] = att_init[n*16+lr]
  {
    float* ag = att_g + (size_t)blk * 4096 + tid * 16;
    #pragma unroll
    for (int n = 0; n < 4; n++) {
      float v0 = att_init[n * 16 + lr];
      #pragma unroll
      for (int v = 0; v < 4; v++) ag[n * 4 + v] = v0;
    }
  }
}

// sequential meta scan
__global__ void k_meta(const int* __restrict__ prog_op, const int* __restrict__ prog_arg,
                       const float* __restrict__ ceout,
                       const float* __restrict__ mw1T, const float* __restrict__ mb1,
                       const float* __restrict__ mw2T, const float* __restrict__ mb2,
                       const float* __restrict__ att_init, float* __restrict__ meta_all) {
  int b = blockIdx.x;
  __shared__ float x[192];
  __shared__ float h[HD];
  __shared__ float meta[AD];
  int tid = threadIdx.x;
  if (tid < AD) meta[tid] = att_init[tid];
  __syncthreads();
  for (int t = 0; t < T; t++) {
    int arg = prog_arg[b * T + t];
    if (tid < AD) x[tid] = meta[tid];
    else if (tid < 192) x[tid] = ceout[arg * E + (tid - 64)];
    __syncthreads();
    float s = mb1[tid];
    for (int c = 0; c < 192; c++) s += x[c] * mw1T[c * HD + tid];
    h[tid] = fmaxf(s, 0.f);
    __syncthreads();
    if (tid < AD) {
      float o = mb2[tid];
      for (int k = 0; k < HD; k++) o += h[k] * mw2T[k * AD + tid];
      float m = (prog_op[b * T + t] == 0) ? 1.f : 0.f;
      float nm = m * o + (1.f - m) * meta[tid];
      meta[tid] = nm;
      meta_all[(t * B + b) * AD + tid] = nm;
    }
    __syncthreads();
  }
}

__global__ void k_proj(const int* __restrict__ prog_arg, const float* __restrict__ ceout,
                       const float* __restrict__ axon, float* __restrict__ proj_all) {
  int gid = blockIdx.x * 4 + (threadIdx.x >> 6);
  int lane = threadIdx.x & 63;
  if (gid >= B * C) return;
  int b = gid / C, i = gid % C;
  float a0 = axon[(size_t)(b * C + i) * E + lane];
  float a1 = axon[(size_t)(b * C + i) * E + 64 + lane];
  for (int t = 0; t < T; t++) {
    int arg = prog_arg[b * T + t];
    float p = a0 * ceout[arg * E + lane] + a1 * ceout[arg * E + 64 + lane];
    for (int off = 1; off < 64; off <<= 1) p += __shfl_xor(p, off, 64);
    if (lane == 0) proj_all[(size_t)(t * B + b) * C + i] = p * (1.f / E);
  }
}

// ---------------- per-step kernel A: Mt[b] = siaT[b] @ axonT[b]^T ----------------
// grid: B*8 blocks; block covers d-range 32 (sub>>1), e-range 64 (sub&1).
// wave w: d 32 rows (2 frags), e rows [e0 + w*16, +16) (1 frag).
__global__ __launch_bounds__(256) void k_M2(const unsigned short* __restrict__ siaT,
                                            const unsigned short* __restrict__ axonT,
                                            unsigned short* __restrict__ Mt) {
  int blk = blockIdx.x;
  int b = blk >> 3, sub = blk & 7;
  int d0 = (sub >> 1) * 32, e0 = (sub & 1) * 64;
  int tid = threadIdx.x;
  int w = tid >> 6, lane = tid & 63, lr = lane & 15, lg = lane >> 4;
  const unsigned short* ap0 = siaT + (size_t)(b * 128 + d0 + lr) * C + lg * 8;
  const unsigned short* ap1 = ap0 + (size_t)16 * C;
  const unsigned short* bp  = axonT + (size_t)(b * E + e0 + w * 16 + lr) * C + lg * 8;
  f32x4 z = {0.f, 0.f, 0.f, 0.f};
  f32x4 acc0 = z, acc1 = z;
  #pragma unroll 4
  for (int k0 = 0; k0 < C; k0 += 32) {
    s16x8 A0 = *(const s16x8*)(ap0 + k0);
    s16x8 A1 = *(const s16x8*)(ap1 + k0);
    s16x8 Bf = *(const s16x8*)(bp + k0);
    acc0 = __builtin_amdgcn_mfma_f32_16x16x32_bf16(A0, Bf, acc0, 0, 0, 0);
    acc1 = __builtin_amdgcn_mfma_f32_16x16x32_bf16(A1, Bf, acc1, 0, 0, 0);
  }
  int ecol = e0 + w * 16 + lr;
  #pragma unroll
  for (int v = 0; v < 4; v++) {
    Mt[(size_t)(b * 128 + d0 + lg * 4 + v) * 128 + ecol]      = f2b(acc0[v]);
    Mt[(size_t)(b * 128 + 16 + d0 + lg * 4 + v) * 128 + ecol] = f2b(acc1[v]);
  }
}

// ---------------- per-step kernel B: gathered -> MLP -> update + hist + next siaT ----
__global__ __launch_bounds__(256) void k_row2(
    int t, const unsigned short* __restrict__ dendron_bf, const unsigned short* __restrict__ Mt,
    const unsigned short* __restrict__ idT_g,
    const unsigned short* __restrict__ w1_bf, const float* __restrict__ b1g,
    const unsigned short* __restrict__ w2_bf, const float* __restrict__ b2g,
    const float* __restrict__ proj_all, const float* __restrict__ meta_all,
    const int* __restrict__ prog_op,
    float* __restrict__ att_g, unsigned short* __restrict__ siaT,
    float* __restrict__ rowmean,
    float* __restrict__ att_hist, float* __restrict__ ins_hist,
    float* __restrict__ trans_hist) {
  const int blk = blockIdx.x;
  const int b = blk / 34, ch = blk % 34, j0 = ch * 64;
  const int tid = threadIdx.x;
  const int w = tid >> 6, lane = tid & 63, lr = lane & 15, lg = lane >> 4;

  __shared__ unsigned short smem[24576];           // 48 KB overlay
  __shared__ float am_l[64];
  unsigned short* g_l = smem;                      // [0,16K)
  unsigned short* mt  = smem + 8192;               // [16K,48K)
  unsigned short* h_l = smem + 8192;               // h overwrites mt

  const f32x4 z = {0.f, 0.f, 0.f, 0.f};

  // load attention state (blocked, coalesced)
  float att[4][4];
  {
    const f32x4* ag = (const f32x4*)(att_g + (size_t)blk * 4096 + tid * 16);
    #pragma unroll
    for (int n = 0; n < 4; n++) {
      f32x4 v4 = ag[n];
      #pragma unroll
      for (int v = 0; v < 4; v++) att[n][v] = v4[v];
    }
  }
  // stage Mt -> LDS (swizzled)
  {
    const unsigned long long* mtp = (const unsigned long long*)(Mt + (size_t)b * 16384);
    #pragma unroll
    for (int k = 0; k < 16; k++) {
      int idx = tid + k * 256;
      unsigned long long v = mtp[idx];
      int r = idx >> 5, c4 = (idx & 31) * 4;
      *(unsigned long long*)&mt[mtidx(r, c4)] = v;
    }
  }
  __syncthreads();
  // ---- phase A: g = dendron @ M / C ----
  {
    s16x8 afr[4];
    #pragma unroll
    for (int ke = 0; ke < 4; ke++)
      afr[ke] = *(const s16x8*)(dendron_bf + (size_t)(b * C + j0 + w * 16 + lr) * E + ke * 32 + lg * 8);
    #pragma unroll
    for (int n = 0; n < 8; n++) {
      f32x4 acc = z;
      #pragma unroll
      for (int ke = 0; ke < 4; ke++) {
        s16x8 bf = *(const s16x8*)&mt[mtidx(n * 16 + lr, ke * 32 + lg * 8)];
        acc = __builtin_amdgcn_mfma_f32_16x16x32_bf16(afr[ke], bf, acc, 0, 0, 0);
      }
      #pragma unroll
      for (int v = 0; v < 4; v++)
        g_l[gidx(w * 16 + lg * 4 + v, n * 16 + lr)] = f2b(acc[v] * (1.f / C));
    }
  }
  __syncthreads();
  // ---- phase B: h = relu(g @ w1^T + b1) ----
  {
    s16x8 gf[4];
    #pragma unroll
    for (int kd = 0; kd < 4; kd++)
      gf[kd] = *(const s16x8*)&g_l[gidx(w * 16 + lr, kd * 32 + lg * 8)];
    #pragma unroll
    for (int n = 0; n < 16; n++) {
      f32x4 acc = z;
      #pragma unroll
      for (int kd = 0; kd < 4; kd++) {
        s16x8 bf = *(const s16x8*)(w1_bf + (size_t)(n * 16 + lr) * E + kd * 32 + lg * 8);
        acc = __builtin_amdgcn_mfma_f32_16x16x32_bf16(gf[kd], bf, acc, 0, 0, 0);
      }
      float b1v = b1g[n * 16 + lr];
      #pragma unroll
      for (int v = 0; v < 4; v++)
        h_l[hidx(w * 16 + lg * 4 + v, n * 16 + lr)] = f2b(fmaxf(acc[v] + b1v, 0.f));
    }
  }
  __syncthreads();
  // ---- phase C: out = h @ w2^T ; update att ; hist ----
  {
    s16x8 hf[8];
    #pragma unroll
    for (int kk = 0; kk < 8; kk++)
      hf[kk] = *(const s16x8*)&h_l[hidx(w * 16 + lr, kk * 32 + lg * 8)];
    int op = prog_op[b * T + t];
    float insF = (op == 1) ? 1.f : 0.f, trF = (op == 2) ? 1.f : 0.f;
    float projv[4];
    #pragma unroll
    for (int v = 0; v < 4; v++)
      projv[v] = proj_all[(size_t)(t * B + b) * C + j0 + w * 16 + lg * 4 + v];
    #pragma unroll
    for (int n = 0; n < 4; n++) {
      f32x4 acc = z;
      #pragma unroll
      for (int kk = 0; kk < 8; kk++) {
        s16x8 bf = *(const s16x8*)(w2_bf + (size_t)(n * 16 + lr) * HD + kk * 32 + lg * 8);
        acc = __builtin_amdgcn_mfma_f32_16x16x32_bf16(hf[kk], bf, acc, 0, 0, 0);
      }
      int a = n * 16 + lr;
      float b2v = b2g[a];
      float meta_a = meta_all[(size_t)(t * B + b) * AD + a];
      #pragma unroll
      for (int v = 0; v < 4; v++) {
        int row = lg * 4 + v;
        int i = j0 + w * 16 + row;
        float transfer = acc[v] + b2v + b2f(g_l[gidx(w * 16 + row, 64 + a)]);
        float insert = meta_a * projv[v];
        float attv = att[n][v] + insF * insert + trF * transfer;
        attv = (attv >= 0.f) ? attv : 0.01f * attv;
        attv = fminf(fmaxf(attv, -1.f), 2.f);
        att[n][v] = attv;
        size_t hi = (((size_t)t * B + b) * C + i) * AD + a;
        __builtin_nontemporal_store(attv, att_hist + hi);
        __builtin_nontemporal_store(insert, ins_hist + hi);
        __builtin_nontemporal_store(transfer, trans_hist + hi);
      }
    }
  }
  // ---- epilogue: amean (shfl), store att_g + satT + rowmean ----
  float amr[4];
  {
    float s[4];
    #pragma unroll
    for (int v = 0; v < 4; v++) s[v] = att[0][v] + att[1][v] + att[2][v] + att[3][v];
    #pragma unroll
    for (int v = 0; v < 4; v++) {
      s[v] += __shfl_xor(s[v], 1, 64);
      s[v] += __shfl_xor(s[v], 2, 64);
      s[v] += __shfl_xor(s[v], 4, 64);
      s[v] += __shfl_xor(s[v], 8, 64);
      amr[v] = s[v] * (1.f / AD);
    }
    if (lr == 0) {
      #pragma unroll
      for (int v = 0; v < 4; v++) {
        am_l[w * 16 + lg * 4 + v] = amr[v];
        rowmean[(size_t)b * C + j0 + w * 16 + lg * 4 + v] = amr[v];
      }
    }
  }
  {
    f32x4* ag = (f32x4*)(att_g + (size_t)blk * 4096 + tid * 16);
    #pragma unroll
    for (int n = 0; n < 4; n++) {
      f32x4 v4;
      #pragma unroll
      for (int v = 0; v < 4; v++) v4[v] = att[n][v];
      ag[n] = v4;
      // satT: siaT[b][64 + n*16+lr][j0 + w*16 + lg*4 + v] = att*amean (4 bf16 packed)
      unsigned long long pk = 0;
      #pragma unroll
      for (int v = 0; v < 4; v++)
        pk |= (unsigned long long)f2b(att[n][v] * amr[v]) << (16 * v);
      *(unsigned long long*)(siaT + (size_t)(b * 128 + 64 + n * 16 + lr) * C + j0 + w * 16 + lg * 4) = pk;
    }
  }
  __syncthreads();
  // ---- id half of next siaT: sidT[d][j] = idT[d][j] * amean[j] ----
  #pragma unroll
  for (int k = 0; k < 2; k++) {
    int idx = tid + k * 256;        // 512 slots: d = idx>>3 (64), part = idx&7
    int d = idx >> 3, part = idx & 7;
    int j = part * 8;
    s16x8 iv = *(const s16x8*)(idT_g + (size_t)(b * 64 + d) * C + j0 + j);
    s16x8 ov;
    #pragma unroll
    for (int m = 0; m < 8; m++)
      ov[m] = (short)f2b(b2f((unsigned short)iv[m]) * am_l[j + m]);
    *(s16x8*)(siaT + (size_t)(b * 128 + d) * C + j0 + j) = ov;
  }
}

// ---------------- final softmax ----------------
__global__ void k_softmax(const float* __restrict__ rowmean, float* __restrict__ out) {
  int b = blockIdx.x;
  __shared__ float am[C];
  __shared__ float red[256];
  int tid = threadIdx.x;
  for (int i = tid; i < C; i += 256) am[i] = rowmean[(size_t)b * C + i];
  __syncthreads();
  float mx = -1e30f;
  for (int i = tid; i < C; i += 256) mx = fmaxf(mx, am[i]);
  red[tid] = mx; __syncthreads();
  for (int s = 128; s > 0; s >>= 1) { if (tid < s) red[tid] = fmaxf(red[tid], red[tid + s]); __syncthreads(); }
  mx = red[0]; __syncthreads();
  float sm = 0.f;
  for (int i = tid; i < C; i += 256) sm += expf(am[i] - mx);
  red[tid] = sm; __syncthreads();
  for (int s = 128; s > 0; s >>= 1) { if (tid < s) red[tid] += red[tid + s]; __syncthreads(); }
  float lse = logf(red[0]) + mx;
  for (int i = tid; i < C; i += 256) out[(size_t)b * C + i] = am[i] - lse;
}

extern "C" void kernel_launch(void* const* d_in, const int* in_sizes, int n_in,
                              void* d_out, int out_size, void* d_ws, size_t ws_size,
                              hipStream_t stream) {
  const int* scene     = (const int*)d_in[0];
  const int* prog_op   = (const int*)d_in[1];
  const int* prog_arg  = (const int*)d_in[2];
  const float* aein    = (const float*)d_in[3];
  const float* aeout   = (const float*)d_in[4];
  const float* aeid    = (const float*)d_in[5];
  const float* cein    = (const float*)d_in[6];
  const float* ceout   = (const float*)d_in[7];
  const float* ceid    = (const float*)d_in[8];
  const float* att_init = (const float*)d_in[11];
  const float* aw1 = (const float*)d_in[12];
  const float* ab1 = (const float*)d_in[13];
  const float* aw2 = (const float*)d_in[14];
  const float* ab2 = (const float*)d_in[15];
  const float* mw1 = (const float*)d_in[16];
  const float* mb1 = (const float*)d_in[17];
  const float* mw2 = (const float*)d_in[18];
  const float* mb2 = (const float*)d_in[19];

  char* ws = (char*)d_ws;
  size_t off = 0;
  auto carve = [&](size_t bytes) { char* p = ws + off; off += (bytes + 255) & ~(size_t)255; return p; };
  float* axon      = (float*)carve((size_t)B * C * E * 4);
  float* identity  = (float*)carve((size_t)B * C * IDD * 4);
  float* proj_all  = (float*)carve((size_t)T * B * C * 4);
  float* meta_all  = (float*)carve((size_t)T * B * AD * 4);
  float* mw1T      = (float*)carve((size_t)192 * HD * 4);
  float* mw2T      = (float*)carve((size_t)HD * AD * 4);
  float* rowmean   = (float*)carve((size_t)B * C * 4);
  float* att_g     = (float*)carve((size_t)272 * 4096 * 4);
  unsigned short* dendron_bf = (unsigned short*)carve((size_t)B * C * E * 2);
  unsigned short* axonT      = (unsigned short*)carve((size_t)B * E * C * 2);
  unsigned short* idT_g      = (unsigned short*)carve((size_t)B * 64 * C * 2);
  unsigned short* siaT       = (unsigned short*)carve((size_t)B * 128 * C * 2);
  unsigned short* Mt         = (unsigned short*)carve((size_t)B * 128 * 128 * 2);
  unsigned short* w1_bf      = (unsigned short*)carve((size_t)HD * E * 2);
  unsigned short* w2_bf      = (unsigned short*)carve((size_t)AD * HD * 2);

  float* out_sm     = (float*)d_out;
  float* att_hist   = out_sm + B * C;
  float* ins_hist   = att_hist + (size_t)T * B * C * AD;
  float* trans_hist = ins_hist + (size_t)T * B * C * AD;

  k_build<<<dim3(B * C), dim3(E), 0, stream>>>(scene, aein, aeout, aeid, cein, ceout, ceid,
                                               dendron_bf, axon, identity);
  k_cvtw<<<dim3(192), dim3(256), 0, stream>>>(aw1, aw2, mw1, mw2, w1_bf, w2_bf, mw1T, mw2T);
  k_transA<<<dim3(B * 34), dim3(256), 0, stream>>>(axon, identity, att_init, axonT, idT_g,
                                                   siaT, att_g);
  k_meta<<<dim3(B), dim3(256), 0, stream>>>(prog_op, prog_arg, ceout, mw1T, mb1, mw2T, mb2,
                                            att_init, meta_all);
  k_proj<<<dim3(B * C / 4), dim3(256), 0, stream>>>(prog_arg, ceout, axon, proj_all);

  for (int t = 0; t < T; t++) {
    k_M2<<<dim3(B * 8), dim3(256), 0, stream>>>(siaT, axonT, Mt);
    k_row2<<<dim3(B * 34), dim3(256), 0, stream>>>(t, dendron_bf, Mt, idT_g,
                                                   w1_bf, ab1, w2_bf, ab2,
                                                   proj_all, meta_all, prog_op,
                                                   att_g, siaT, rowmean,
                                                   att_hist, ins_hist, trans_hist);
  }
  k_softmax<<<dim3(B), dim3(256), 0, stream>>>(rowmean, out_sm);
}

// Round 7
// 655.423 us; speedup vs baseline: 8.0282x; 1.2998x over previous
//
#include <hip/hip_runtime.h>

#define B 8
#define NOBJ 128
#define NATTR 4
#define T 12
#define MC 2048
#define E 128
#define IDD 64
#define AD 64
#define HD 256
#define C 2176

typedef short s16x8 __attribute__((ext_vector_type(8)));
typedef float f32x4 __attribute__((ext_vector_type(4)));

__device__ inline unsigned short f2b(float f) {
  union { float f; unsigned u; } v; v.f = f;
  unsigned r = v.u + 0x7FFFu + ((v.u >> 16) & 1u);
  return (unsigned short)(r >> 16);
}
__device__ inline float b2f(unsigned short u) {
  union { unsigned u; float f; } v; v.u = ((unsigned)u) << 16;
  return v.f;
}

// coherent (MALL-routed) accessors: bypass non-coherent per-XCD L1/L2, no fences
__device__ __forceinline__ void st_coh_u64(unsigned long long* p, unsigned long long v) {
  __hip_atomic_store(p, v, __ATOMIC_RELAXED, __HIP_MEMORY_SCOPE_AGENT);
}
__device__ __forceinline__ unsigned long long ld_coh_u64(const unsigned long long* p) {
  return __hip_atomic_load(p, __ATOMIC_RELAXED, __HIP_MEMORY_SCOPE_AGENT);
}
__device__ __forceinline__ void st_coh_u32(unsigned* p, unsigned v) {
  __hip_atomic_store(p, v, __ATOMIC_RELAXED, __HIP_MEMORY_SCOPE_AGENT);
}
__device__ __forceinline__ unsigned ld_coh_u32(const unsigned* p) {
  return __hip_atomic_load(p, __ATOMIC_RELAXED, __HIP_MEMORY_SCOPE_AGENT);
}

// LDS swizzles: XOR row bits into the 16B-slot index (conflict-free b128 reads)
__device__ __forceinline__ int gidx(int r, int c) {   // g [64][128]
  return r * 128 + ((((c >> 3) ^ (r & 15)) << 3) | (c & 7));
}
__device__ __forceinline__ int hidx(int r, int c) {   // h [64][256]
  return r * 256 + ((((c >> 3) ^ (r & 15)) << 3) | (c & 7));
}
__device__ __forceinline__ int mtidx(int r, int c) {  // mt [128][128]
  return r * 128 + ((((c >> 3) ^ (r & 15)) << 3) | (c & 7));
}

// ---------------- setup kernel 1: build + weight cvt + flag zero ----------------
__global__ __launch_bounds__(256) void k_setup1(
    const int* __restrict__ scene,
    const float* __restrict__ aein, const float* __restrict__ aeout,
    const float* __restrict__ aeid,
    const float* __restrict__ cein, const float* __restrict__ ceout,
    const float* __restrict__ ceid,
    const float* __restrict__ aw1, const float* __restrict__ aw2,
    const float* __restrict__ mw1, const float* __restrict__ mw2,
    unsigned short* __restrict__ dendron_bf, float* __restrict__ axon,
    float* __restrict__ identity,
    unsigned short* __restrict__ w1_bf, unsigned short* __restrict__ w2_bf,
    float* __restrict__ mw1T, float* __restrict__ mw2T,
    unsigned* __restrict__ mflag) {
  int blk = blockIdx.x;
  int tid = threadIdx.x;
  if (blk < 4352) {
    // build: 2 (b,j) rows per block
    int gid = blk * 2 + (tid >> 7);
    int e = tid & 127;
    int b = gid / C, j = gid % C;
    float din, dout, did = 0.f;
    if (j < MC) {
      din  = cein[j * E + e];
      dout = ceout[j * E + e];
      if (e < IDD) did = ceid[j * IDD + e];
    } else {
      int obj = j - MC;
      float sIn = 0.f, sOut = 0.f, sId = 0.f;
      for (int a = 0; a < NATTR; a++) {
        int s = scene[(b * NOBJ + obj) * NATTR + a];
        float m = (s != -1) ? 1.f : 0.f;
        int idx = s + 1;
        sIn  += aein[idx * E + e] * m;
        sOut += aeout[idx * E + e] * m;
        if (e < IDD) sId += aeid[idx * IDD + e] * m;
      }
      din = sIn; dout = sOut; did = sId;
    }
    dendron_bf[(size_t)gid * E + e] = f2b(din);
    axon[(size_t)gid * E + e] = dout;
    if (e < IDD) identity[(size_t)gid * IDD + e] = did;
  } else if (blk < 4544) {
    int i = (blk - 4352) * 256 + tid;
    if (i < HD * E)  w1_bf[i] = f2b(aw1[i]);
    if (i < AD * HD) w2_bf[i] = f2b(aw2[i]);
    if (i < 192 * HD) { int c = i / HD, k = i % HD; mw1T[c * HD + k] = mw1[k * 192 + c]; }
    if (i < HD * AD)  { int k = i / AD, a = i % AD; mw2T[k * AD + a] = mw2[a * HD + k]; }
  } else {
    if (tid < B * 16) mflag[tid] = 0u;
  }
}

// ---------------- setup kernel 2: transA/init + meta + proj ----------------
__global__ __launch_bounds__(256) void k_setup2(
    const float* __restrict__ axon, const float* __restrict__ identity,
    const float* __restrict__ att_init,
    const int* __restrict__ prog_op, const int* __restrict__ prog_arg,
    const float* __restrict__ ceout,
    const float* __restrict__ mw1T, const float* __restrict__ mb1,
    const float* __restrict__ mw2T, const float* __restrict__ mb2,
    unsigned short* __restrict__ axonT, unsigned short* __restrict__ idT_g,
    unsigned short* __restrict__ siaT, float* __restrict__ att_g,
    float* __restrict__ meta_all, float* __restrict__ proj_all) {
  int blk = blockIdx.x;
  int tid = threadIdx.x;
  if (blk < 272) {
    // transpose + state init
    int b = blk / 34, jc = blk % 34;
    int j0 = jc * 64;
    __shared__ float ax[64][129];
    __shared__ float idb[64][65];
    int lane = tid & 63, lr = lane & 15;
    float s = att_init[lane];
    s += __shfl_xor(s, 1, 64);  s += __shfl_xor(s, 2, 64);
    s += __shfl_xor(s, 4, 64);  s += __shfl_xor(s, 8, 64);
    s += __shfl_xor(s, 16, 64); s += __shfl_xor(s, 32, 64);
    float am0 = s * (1.f / AD);
    for (int i = tid; i < 64 * 128; i += 256) {
      int j = i >> 7, e = i & 127;
      ax[j][e] = axon[(size_t)(b * C + j0 + j) * E + e];
    }
    for (int i = tid; i < 64 * 64; i += 256) {
      int j = i >> 6, d = i & 63;
      idb[j][d] = identity[(size_t)(b * C + j0 + j) * IDD + d];
    }
    __syncthreads();
    for (int i = tid; i < 128 * 64; i += 256) {
      int e = i >> 6, jj = i & 63;
      axonT[(size_t)(b * E + e) * C + j0 + jj] = f2b(ax[jj][e]);
    }
    for (int i = tid; i < 64 * 64; i += 256) {
      int d = i >> 6, jj = i & 63;
      idT_g[(size_t)(b * 64 + d) * C + j0 + jj] = f2b(idb[jj][d]);
      siaT[(size_t)(b * 128 + d) * C + j0 + jj] = f2b(idb[jj][d] * am0);
      siaT[(size_t)(b * 128 + 64 + d) * C + j0 + jj] = f2b(att_init[d] * am0);
    }
    {
      float* ag = att_g + (size_t)blk * 4096 + tid * 16;
      #pragma unroll
      for (int n = 0; n < 4; n++) {
        float v0 = att_init[n * 16 + lr];
        #pragma unroll
        for (int v = 0; v < 4; v++) ag[n * 4 + v] = v0;
      }
    }
  } else if (blk < 280) {
    // meta scan
    int b = blk - 272;
    __shared__ float x[192];
    __shared__ float h[HD];
    __shared__ float meta[AD];
    if (tid < AD) meta[tid] = att_init[tid];
    __syncthreads();
    for (int t = 0; t < T; t++) {
      int arg = prog_arg[b * T + t];
      if (tid < AD) x[tid] = meta[tid];
      else if (tid < 192) x[tid] = ceout[arg * E + (tid - 64)];
      __syncthreads();
      float s = mb1[tid];
      for (int c = 0; c < 192; c++) s += x[c] * mw1T[c * HD + tid];
      h[tid] = fmaxf(s, 0.f);
      __syncthreads();
      if (tid < AD) {
        float o = mb2[tid];
        for (int k = 0; k < HD; k++) o += h[k] * mw2T[k * AD + tid];
        float m = (prog_op[b * T + t] == 0) ? 1.f : 0.f;
        float nm = m * o + (1.f - m) * meta[tid];
        meta[tid] = nm;
        meta_all[(t * B + b) * AD + tid] = nm;
      }
      __syncthreads();
    }
  } else {
    // proj
    int gid = (blk - 280) * 4 + (tid >> 6);
    int lane = tid & 63;
    int b = gid / C, i = gid % C;
    float a0 = axon[(size_t)gid * E + lane];
    float a1 = axon[(size_t)gid * E + 64 + lane];
    for (int t = 0; t < T; t++) {
      int arg = prog_arg[b * T + t];
      float p = a0 * ceout[arg * E + lane] + a1 * ceout[arg * E + 64 + lane];
      for (int off = 1; off < 64; off <<= 1) p += __shfl_xor(p, off, 64);
      if (lane == 0) proj_all[(size_t)(t * B + b) * C + i] = p * (1.f / E);
    }
  }
}

// ---------------- fused per-step kernel ----------------
// blocks 34 per batch; ch<16 also produce one 32x32 M-tile first.
__global__ __launch_bounds__(256) void k_step(
    int t,
    const unsigned short* __restrict__ dendron_bf,
    const unsigned short* __restrict__ axonT,
    const unsigned short* __restrict__ idT_g,
    const unsigned short* __restrict__ siaT_in,
    const unsigned short* __restrict__ w1_bf, const float* __restrict__ b1g,
    const unsigned short* __restrict__ w2_bf, const float* __restrict__ b2g,
    const float* __restrict__ proj_all, const float* __restrict__ meta_all,
    const int* __restrict__ prog_op,
    unsigned long long* __restrict__ Mt64,
    float* __restrict__ att_g, unsigned short* __restrict__ siaT_out,
    float* __restrict__ rowmean,
    float* __restrict__ att_hist, float* __restrict__ ins_hist,
    float* __restrict__ trans_hist,
    unsigned* __restrict__ mflag) {
  const int blk = blockIdx.x;
  const int b = blk / 34, ch = blk % 34, j0 = ch * 64;
  const int tid = threadIdx.x;
  const int w = tid >> 6, lane = tid & 63, lr = lane & 15, lg = lane >> 4;

  __shared__ unsigned short smem[24576];           // 48 KB overlay
  __shared__ float am_l[64];
  unsigned short* g_l = smem;                      // bytes [0,16K)
  unsigned short* mt  = smem + 8192;               // bytes [16K,48K)
  unsigned short* h_l = smem + 8192;
  float* mred = (float*)smem;                      // producer scratch [4][32][33]

  const f32x4 z = {0.f, 0.f, 0.f, 0.f};
  const unsigned ph = (unsigned)(t + 1);

  // load attention state early (independent of M)
  float att[4][4];
  {
    const f32x4* ag = (const f32x4*)(att_g + (size_t)blk * 4096 + tid * 16);
    #pragma unroll
    for (int n = 0; n < 4; n++) {
      f32x4 v4 = ag[n];
      #pragma unroll
      for (int v = 0; v < 4; v++) att[n][v] = v4[v];
    }
  }

  // ---- producers: ch<16 compute one 32x32 tile of M = siaT @ axonT^T ----
  if (ch < 16) {
    int d0 = (ch >> 2) * 32, e0 = (ch & 3) * 32;
    const unsigned short* ap0 = siaT_in + (size_t)(b * 128 + d0 + lr) * C + w * 544 + lg * 8;
    const unsigned short* ap1 = ap0 + (size_t)16 * C;
    const unsigned short* bp0 = axonT + (size_t)(b * E + e0 + lr) * C + w * 544 + lg * 8;
    const unsigned short* bp1 = bp0 + (size_t)16 * C;
    f32x4 a00 = z, a01 = z, a10 = z, a11 = z;
    #pragma unroll 4
    for (int kk = 0; kk < 17; kk++) {
      int k0 = kk * 32;
      s16x8 A0 = *(const s16x8*)(ap0 + k0);
      s16x8 A1 = *(const s16x8*)(ap1 + k0);
      s16x8 B0 = *(const s16x8*)(bp0 + k0);
      s16x8 B1 = *(const s16x8*)(bp1 + k0);
      a00 = __builtin_amdgcn_mfma_f32_16x16x32_bf16(A0, B0, a00, 0, 0, 0);
      a01 = __builtin_amdgcn_mfma_f32_16x16x32_bf16(A0, B1, a01, 0, 0, 0);
      a10 = __builtin_amdgcn_mfma_f32_16x16x32_bf16(A1, B0, a10, 0, 0, 0);
      a11 = __builtin_amdgcn_mfma_f32_16x16x32_bf16(A1, B1, a11, 0, 0, 0);
    }
    // store partials to LDS [4][32][33]
    #pragma unroll
    for (int v = 0; v < 4; v++) {
      mred[(w * 32 + lg * 4 + v) * 33 + lr]          = a00[v];
      mred[(w * 32 + lg * 4 + v) * 33 + 16 + lr]     = a01[v];
      mred[(w * 32 + 16 + lg * 4 + v) * 33 + lr]     = a10[v];
      mred[(w * 32 + 16 + lg * 4 + v) * 33 + 16 + lr] = a11[v];
    }
    __syncthreads();
    // reduce across 4 waves, pack 4 bf16, coherent store
    {
      int r = tid >> 3, c = (tid & 7) * 4;
      float s0 = 0.f, s1 = 0.f, s2 = 0.f, s3 = 0.f;
      #pragma unroll
      for (int w4 = 0; w4 < 4; w4++) {
        const float* p = &mred[(w4 * 32 + r) * 33 + c];
        s0 += p[0]; s1 += p[1]; s2 += p[2]; s3 += p[3];
      }
      unsigned long long pk = (unsigned long long)f2b(s0)
                            | ((unsigned long long)f2b(s1) << 16)
                            | ((unsigned long long)f2b(s2) << 32)
                            | ((unsigned long long)f2b(s3) << 48);
      st_coh_u64(Mt64 + (((size_t)(b * 128 + d0 + r) * 128) + e0 + c) / 4, pk);
    }
    asm volatile("s_waitcnt vmcnt(0)" ::: "memory");
    __syncthreads();
    if (tid == 0) st_coh_u32(mflag + b * 16 + ch, ph);
  }
  // ---- all blocks: wait for this batch's 16 M-tiles ----
  if (tid < 16) {
    while (ld_coh_u32(mflag + b * 16 + tid) < ph) __builtin_amdgcn_s_sleep(1);
  }
  __syncthreads();
  // ---- stage Mt -> LDS (swizzled, coherent loads) ----
  {
    const unsigned long long* mtp = Mt64 + (size_t)b * 4096;
    #pragma unroll
    for (int k = 0; k < 16; k++) {
      int idx = tid + k * 256;
      unsigned long long v = ld_coh_u64(mtp + idx);
      int r = idx >> 5, c4 = (idx & 31) * 4;
      *(unsigned long long*)&mt[mtidx(r, c4)] = v;
    }
  }
  __syncthreads();
  // ---- phase A: g = dendron @ M / C ----
  {
    s16x8 afr[4];
    #pragma unroll
    for (int ke = 0; ke < 4; ke++)
      afr[ke] = *(const s16x8*)(dendron_bf + (size_t)(b * C + j0 + w * 16 + lr) * E + ke * 32 + lg * 8);
    #pragma unroll
    for (int n = 0; n < 8; n++) {
      f32x4 acc = z;
      #pragma unroll
      for (int ke = 0; ke < 4; ke++) {
        s16x8 bf = *(const s16x8*)&mt[mtidx(n * 16 + lr, ke * 32 + lg * 8)];
        acc = __builtin_amdgcn_mfma_f32_16x16x32_bf16(afr[ke], bf, acc, 0, 0, 0);
      }
      #pragma unroll
      for (int v = 0; v < 4; v++)
        g_l[gidx(w * 16 + lg * 4 + v, n * 16 + lr)] = f2b(acc[v] * (1.f / C));
    }
  }
  __syncthreads();
  // ---- phase B: h = relu(g @ w1^T + b1) ----
  {
    s16x8 gf[4];
    #pragma unroll
    for (int kd = 0; kd < 4; kd++)
      gf[kd] = *(const s16x8*)&g_l[gidx(w * 16 + lr, kd * 32 + lg * 8)];
    #pragma unroll
    for (int n = 0; n < 16; n++) {
      f32x4 acc = z;
      #pragma unroll
      for (int kd = 0; kd < 4; kd++) {
        s16x8 bf = *(const s16x8*)(w1_bf + (size_t)(n * 16 + lr) * E + kd * 32 + lg * 8);
        acc = __builtin_amdgcn_mfma_f32_16x16x32_bf16(gf[kd], bf, acc, 0, 0, 0);
      }
      float b1v = b1g[n * 16 + lr];
      #pragma unroll
      for (int v = 0; v < 4; v++)
        h_l[hidx(w * 16 + lg * 4 + v, n * 16 + lr)] = f2b(fmaxf(acc[v] + b1v, 0.f));
    }
  }
  __syncthreads();
  // ---- phase C: out = h @ w2^T ; update att ; hist ----
  {
    s16x8 hf[8];
    #pragma unroll
    for (int kk = 0; kk < 8; kk++)
      hf[kk] = *(const s16x8*)&h_l[hidx(w * 16 + lr, kk * 32 + lg * 8)];
    int op = prog_op[b * T + t];
    float insF = (op == 1) ? 1.f : 0.f, trF = (op == 2) ? 1.f : 0.f;
    float projv[4];
    #pragma unroll
    for (int v = 0; v < 4; v++)
      projv[v] = proj_all[(size_t)(t * B + b) * C + j0 + w * 16 + lg * 4 + v];
    #pragma unroll
    for (int n = 0; n < 4; n++) {
      f32x4 acc = z;
      #pragma unroll
      for (int kk = 0; kk < 8; kk++) {
        s16x8 bf = *(const s16x8*)(w2_bf + (size_t)(n * 16 + lr) * HD + kk * 32 + lg * 8);
        acc = __builtin_amdgcn_mfma_f32_16x16x32_bf16(hf[kk], bf, acc, 0, 0, 0);
      }
      int a = n * 16 + lr;
      float b2v = b2g[a];
      float meta_a = meta_all[(size_t)(t * B + b) * AD + a];
      #pragma unroll
      for (int v = 0; v < 4; v++) {
        int row = lg * 4 + v;
        int i = j0 + w * 16 + row;
        float transfer = acc[v] + b2v + b2f(g_l[gidx(w * 16 + row, 64 + a)]);
        float insert = meta_a * projv[v];
        float attv = att[n][v] + insF * insert + trF * transfer;
        attv = (attv >= 0.f) ? attv : 0.01f * attv;
        attv = fminf(fmaxf(attv, -1.f), 2.f);
        att[n][v] = attv;
        size_t hi = (((size_t)t * B + b) * C + i) * AD + a;
        __builtin_nontemporal_store(attv, att_hist + hi);
        __builtin_nontemporal_store(insert, ins_hist + hi);
        __builtin_nontemporal_store(transfer, trans_hist + hi);
      }
    }
  }
  // ---- epilogue: amean, store att_g + att-half of next siaT + rowmean ----
  float amr[4];
  {
    float s[4];
    #pragma unroll
    for (int v = 0; v < 4; v++) s[v] = att[0][v] + att[1][v] + att[2][v] + att[3][v];
    #pragma unroll
    for (int v = 0; v < 4; v++) {
      s[v] += __shfl_xor(s[v], 1, 64);
      s[v] += __shfl_xor(s[v], 2, 64);
      s[v] += __shfl_xor(s[v], 4, 64);
      s[v] += __shfl_xor(s[v], 8, 64);
      amr[v] = s[v] * (1.f / AD);
    }
    if (lr == 0) {
      #pragma unroll
      for (int v = 0; v < 4; v++) {
        am_l[w * 16 + lg * 4 + v] = amr[v];
        rowmean[(size_t)b * C + j0 + w * 16 + lg * 4 + v] = amr[v];
      }
    }
  }
  {
    f32x4* ag = (f32x4*)(att_g + (size_t)blk * 4096 + tid * 16);
    #pragma unroll
    for (int n = 0; n < 4; n++) {
      f32x4 v4;
      #pragma unroll
      for (int v = 0; v < 4; v++) v4[v] = att[n][v];
      ag[n] = v4;
      unsigned long long pk = 0;
      #pragma unroll
      for (int v = 0; v < 4; v++)
        pk |= (unsigned long long)f2b(att[n][v] * amr[v]) << (16 * v);
      *(unsigned long long*)(siaT_out + (size_t)(b * 128 + 64 + n * 16 + lr) * C + j0 + w * 16 + lg * 4) = pk;
    }
  }
  __syncthreads();
  // ---- id half of next siaT ----
  #pragma unroll
  for (int k = 0; k < 2; k++) {
    int idx = tid + k * 256;
    int d = idx >> 3, part = idx & 7;
    int j = part * 8;
    s16x8 iv = *(const s16x8*)(idT_g + (size_t)(b * 64 + d) * C + j0 + j);
    s16x8 ov;
    #pragma unroll
    for (int m = 0; m < 8; m++)
      ov[m] = (short)f2b(b2f((unsigned short)iv[m]) * am_l[j + m]);
    *(s16x8*)(siaT_out + (size_t)(b * 128 + d) * C + j0 + j) = ov;
  }
}

// ---------------- final softmax ----------------
__global__ void k_softmax(const float* __restrict__ rowmean, float* __restrict__ out) {
  int b = blockIdx.x;
  __shared__ float am[C];
  __shared__ float red[256];
  int tid = threadIdx.x;
  for (int i = tid; i < C; i += 256) am[i] = rowmean[(size_t)b * C + i];
  __syncthreads();
  float mx = -1e30f;
  for (int i = tid; i < C; i += 256) mx = fmaxf(mx, am[i]);
  red[tid] = mx; __syncthreads();
  for (int s = 128; s > 0; s >>= 1) { if (tid < s) red[tid] = fmaxf(red[tid], red[tid + s]); __syncthreads(); }
  mx = red[0]; __syncthreads();
  float sm = 0.f;
  for (int i = tid; i < C; i += 256) sm += expf(am[i] - mx);
  red[tid] = sm; __syncthreads();
  for (int s = 128; s > 0; s >>= 1) { if (tid < s) red[tid] += red[tid + s]; __syncthreads(); }
  float lse = logf(red[0]) + mx;
  for (int i = tid; i < C; i += 256) out[(size_t)b * C + i] = am[i] - lse;
}

extern "C" void kernel_launch(void* const* d_in, const int* in_sizes, int n_in,
                              void* d_out, int out_size, void* d_ws, size_t ws_size,
                              hipStream_t stream) {
  const int* scene     = (const int*)d_in[0];
  const int* prog_op   = (const int*)d_in[1];
  const int* prog_arg  = (const int*)d_in[2];
  const float* aein    = (const float*)d_in[3];
  const float* aeout   = (const float*)d_in[4];
  const float* aeid    = (const float*)d_in[5];
  const float* cein    = (const float*)d_in[6];
  const float* ceout   = (const float*)d_in[7];
  const float* ceid    = (const float*)d_in[8];
  const float* att_init = (const float*)d_in[11];
  const float* aw1 = (const float*)d_in[12];
  const float* ab1 = (const float*)d_in[13];
  const float* aw2 = (const float*)d_in[14];
  const float* ab2 = (const float*)d_in[15];
  const float* mw1 = (const float*)d_in[16];
  const float* mb1 = (const float*)d_in[17];
  const float* mw2 = (const float*)d_in[18];
  const float* mb2 = (const float*)d_in[19];

  char* ws = (char*)d_ws;
  size_t off = 0;
  auto carve = [&](size_t bytes) { char* p = ws + off; off += (bytes + 255) & ~(size_t)255; return p; };
  float* axon      = (float*)carve((size_t)B * C * E * 4);
  float* identity  = (float*)carve((size_t)B * C * IDD * 4);
  float* proj_all  = (float*)carve((size_t)T * B * C * 4);
  float* meta_all  = (float*)carve((size_t)T * B * AD * 4);
  float* mw1T      = (float*)carve((size_t)192 * HD * 4);
  float* mw2T      = (float*)carve((size_t)HD * AD * 4);
  float* rowmean   = (float*)carve((size_t)B * C * 4);
  float* att_g     = (float*)carve((size_t)272 * 4096 * 4);
  unsigned short* dendron_bf = (unsigned short*)carve((size_t)B * C * E * 2);
  unsigned short* axonT      = (unsigned short*)carve((size_t)B * E * C * 2);
  unsigned short* idT_g      = (unsigned short*)carve((size_t)B * 64 * C * 2);
  unsigned short* siaT       = (unsigned short*)carve((size_t)B * 128 * C * 2);
  unsigned long long* Mt64   = (unsigned long long*)carve((size_t)B * 4096 * 8);
  unsigned short* w1_bf      = (unsigned short*)carve((size_t)HD * E * 2);
  unsigned short* w2_bf      = (unsigned short*)carve((size_t)AD * HD * 2);
  unsigned*       mflag      = (unsigned*)carve(1024);

  float* out_sm     = (float*)d_out;
  float* att_hist   = out_sm + B * C;
  float* ins_hist   = att_hist + (size_t)T * B * C * AD;
  float* trans_hist = ins_hist + (size_t)T * B * C * AD;

  k_setup1<<<dim3(4545), dim3(256), 0, stream>>>(scene, aein, aeout, aeid, cein, ceout, ceid,
                                                 aw1, aw2, mw1, mw2,
                                                 dendron_bf, axon, identity,
                                                 w1_bf, w2_bf, mw1T, mw2T, mflag);
  k_setup2<<<dim3(1368), dim3(256), 0, stream>>>(axon, identity, att_init,
                                                 prog_op, prog_arg, ceout,
                                                 mw1T, mb1, mw2T, mb2,
                                                 axonT, idT_g, siaT, att_g,
                                                 meta_all, proj_all);
  for (int t = 0; t < T; t++) {
    k_step<<<dim3(272), dim3(256), 0, stream>>>(t, dendron_bf, axonT, idT_g, siaT,
                                                w1_bf, ab1, w2_bf, ab2,
                                                proj_all, meta_all, prog_op,
                                                Mt64, att_g, siaT, rowmean,
                                                att_hist, ins_hist, trans_hist, mflag);
  }
  k_softmax<<<dim3(B), dim3(256), 0, stream>>>(rowmean, out_sm);
}